// Round 4
// baseline (315.302 us; speedup 1.0000x reference)
//
#include <hip/hip_runtime.h>
#include <hip/hip_bf16.h>
#include <stdint.h>

#define BB 4
#define TSEQ 512
#define NSEQ 512
#define DD 1024
#define EE 1024
#define HH 16
#define HD 64

typedef __attribute__((ext_vector_type(8))) short bf16x8;
typedef __attribute__((ext_vector_type(4))) float f32x4;

__device__ __forceinline__ unsigned short f2bf(float f) {
    union { float f; uint32_t u; } v; v.f = f;
    uint32_t u = v.u;
    uint32_t r = (u + 0x7fffu + ((u >> 16) & 1u)) >> 16;
    return (unsigned short)r;
}

__device__ __forceinline__ uint32_t pkbf(float a, float b) {
    __hip_bfloat162 t = __float22bfloat162_rn(float2{a, b});
    return *(uint32_t*)&t;
}

#define GLD16(gp, lp)                                                          \
    __builtin_amdgcn_global_load_lds(                                          \
        (const __attribute__((address_space(1))) unsigned int*)(gp),           \
        (__attribute__((address_space(3))) unsigned int*)(lp), 16, 0, 0)

// ---------------------------------------------------------------------------
// K1: prep = weight transpose/cvt (blocks 0..2047) + adaln (blocks 2048..2303)
// ---------------------------------------------------------------------------
__global__ __launch_bounds__(256) void prep_kernel(
    const float* __restrict__ q_w, const float* __restrict__ k_w,
    const float* __restrict__ v_w, const float* __restrict__ out_w,
    unsigned short* __restrict__ qwt, unsigned short* __restrict__ kwt,
    unsigned short* __restrict__ vwt, unsigned short* __restrict__ owt,
    const float* __restrict__ emb,
    const float* __restrict__ adaln_w, const float* __restrict__ adaln_b,
    const float* __restrict__ xf_w, const float* __restrict__ xf_b,
    float* __restrict__ scaleB, float* __restrict__ shiftB)
{
    __shared__ __align__(16) char smem[33280];
    int bx = blockIdx.x, tid = threadIdx.x;
    if (bx < 2048) {
        // ---- weight transpose: W[k][n] fp32 -> WT[n][k] bf16, 64x64 tile ----
        unsigned short* Ts = (unsigned short*)smem;   // 64*72
        int z = bx >> 8, tile = bx & 255;
        int k0 = (tile >> 4) * 64, n0 = (tile & 15) * 64;
        const float* in; unsigned short* out;
        if (z < 3)       { in = q_w + (size_t)z * DD * DD;         out = qwt + (size_t)z * DD * DD; }
        else if (z == 3) { in = k_w;                               out = kwt; }
        else if (z == 4) { in = v_w;                               out = vwt; }
        else             { in = out_w + (size_t)(z - 5) * DD * DD; out = owt + (size_t)(z - 5) * DD * DD; }
        int r = tid >> 2, c0 = (tid & 3) * 16;
#pragma unroll
        for (int i = 0; i < 4; i++) {
            float4 v = *(const float4*)(in + (size_t)(k0 + r) * DD + n0 + c0 + i * 4);
            Ts[(c0 + i * 4 + 0) * 72 + r] = f2bf(v.x);
            Ts[(c0 + i * 4 + 1) * 72 + r] = f2bf(v.y);
            Ts[(c0 + i * 4 + 2) * 72 + r] = f2bf(v.z);
            Ts[(c0 + i * 4 + 3) * 72 + r] = f2bf(v.w);
        }
        __syncthreads();
#pragma unroll
        for (int i = 0; i < 2; i++) {
            int idx = i * 256 + tid;
            int row = idx >> 3, ko = (idx & 7) * 8;
            *(uint4*)(out + (size_t)(n0 + row) * DD + k0 + ko) =
                *(const uint4*)(Ts + row * 72 + ko);
        }
    } else {
        // ---- adaln: 32 cols x 4 batches per block, W read once ----
        float (*seT)[4] = (float(*)[4])smem;          // 16384 B
        float* buf = (float*)(smem + 16384);          // 128*33*4 = 16896 B
        int idx = bx - 2048;
        int chunk = idx >> 2, j = idx & 3;
#pragma unroll
        for (int b = 0; b < 4; b++) {
            float4 e4 = ((const float4*)(emb + (size_t)b * EE))[tid];
            seT[tid * 4 + 0][b] = e4.x / (1.f + __expf(-e4.x));
            seT[tid * 4 + 1][b] = e4.y / (1.f + __expf(-e4.y));
            seT[tid * 4 + 2][b] = e4.z / (1.f + __expf(-e4.z));
            seT[tid * 4 + 3][b] = e4.w / (1.f + __expf(-e4.w));
        }
        __syncthreads();
        const float* W    = (j < 3) ? (adaln_w + (size_t)j * EE * 2 * DD) : xf_w;
        const float* bias = (j < 3) ? (adaln_b + (size_t)j * 2 * DD) : xf_b;
        int eg = tid >> 3, cg = tid & 7;
        int c0 = chunk * 32 + cg * 4;
        const float* Wp = W + (size_t)(eg * 32) * (2 * DD) + c0;
        float4 a0 = {0,0,0,0}, a1 = {0,0,0,0}, a2 = {0,0,0,0}, a3 = {0,0,0,0};
#pragma unroll 8
        for (int e = 0; e < 32; e++) {
            float4 w = *(const float4*)(Wp + (size_t)e * (2 * DD));
            float4 s = *(const float4*)&seT[eg * 32 + e][0];
            a0.x += s.x * w.x; a0.y += s.x * w.y; a0.z += s.x * w.z; a0.w += s.x * w.w;
            a1.x += s.y * w.x; a1.y += s.y * w.y; a1.z += s.y * w.z; a1.w += s.y * w.w;
            a2.x += s.z * w.x; a2.y += s.z * w.y; a2.z += s.z * w.z; a2.w += s.z * w.w;
            a3.x += s.w * w.x; a3.y += s.w * w.y; a3.z += s.w * w.z; a3.w += s.w * w.w;
        }
        float accs[4][4] = {{a0.x,a0.y,a0.z,a0.w},{a1.x,a1.y,a1.z,a1.w},
                            {a2.x,a2.y,a2.z,a2.w},{a3.x,a3.y,a3.z,a3.w}};
#pragma unroll
        for (int b = 0; b < 4; b++)
#pragma unroll
            for (int i = 0; i < 4; i++)
                buf[(b * 32 + cg * 4 + i) * 33 + eg] = accs[b][i];
        __syncthreads();
        if (tid < 128) {
            int b = tid >> 5, cl = tid & 31;
            float s = 0.f;
#pragma unroll 8
            for (int e = 0; e < 32; e++) s += buf[(b * 32 + cl) * 33 + e];
            int c = chunk * 32 + cl;
            float v = s + bias[c];
            if (c < DD) scaleB[(size_t)(j * 4 + b) * DD + c] = v;
            else        shiftB[(size_t)(j * 4 + b) * DD + (c - DD)] = v;
        }
    }
}

// ---------------------------------------------------------------------------
// K2: LayerNorm + modulate, cast bf16
// ---------------------------------------------------------------------------
__global__ __launch_bounds__(256) void ln_mod_kernel(
    const float* __restrict__ x1, const float* __restrict__ x2,
    const float* __restrict__ x3, const float* __restrict__ xf,
    const float* __restrict__ scaleB, const float* __restrict__ shiftB,
    unsigned short* __restrict__ hq, unsigned short* __restrict__ hx)
{
    __shared__ float rs[4], rq[4];
    int row = blockIdx.x, tid = threadIdx.x;
    const float* src; unsigned short* dst; int sb;
    if (row < 6144) {
        int b = row / 1536, t3 = row % 1536;
        int br = t3 >> 9, t = t3 & 511;
        const float* xs = (br == 0) ? x1 : ((br == 1) ? x2 : x3);
        src = xs + ((size_t)b * TSEQ + t) * DD;
        dst = hq + (size_t)row * DD;
        sb = br * 4 + b;
    } else {
        int idx = row - 6144;
        src = xf + (size_t)idx * DD;
        dst = hx + (size_t)idx * DD;
        sb = 12 + (idx >> 9);
    }
    float4 x = ((const float4*)src)[tid];
    float s = x.x + x.y + x.z + x.w;
    float q = x.x * x.x + x.y * x.y + x.z * x.z + x.w * x.w;
    for (int o = 1; o < 64; o <<= 1) { s += __shfl_xor(s, o, 64); q += __shfl_xor(q, o, 64); }
    int lane = tid & 63, wid = tid >> 6;
    if (lane == 0) { rs[wid] = s; rq[wid] = q; }
    __syncthreads();
    float S = rs[0] + rs[1] + rs[2] + rs[3];
    float Q = rq[0] + rq[1] + rq[2] + rq[3];
    float mu = S * (1.f / DD);
    float var = Q * (1.f / DD) - mu * mu;
    float rstd = rsqrtf(var + 1e-6f);
    float4 sc = ((const float4*)(scaleB + (size_t)sb * DD))[tid];
    float4 sh = ((const float4*)(shiftB + (size_t)sb * DD))[tid];
    ushort4 o;
    o.x = f2bf((x.x - mu) * rstd * (1.f + sc.x) + sh.x);
    o.y = f2bf((x.y - mu) * rstd * (1.f + sc.y) + sh.y);
    o.z = f2bf((x.z - mu) * rstd * (1.f + sc.z) + sh.z);
    o.w = f2bf((x.w - mu) * rstd * (1.f + sc.w) + sh.w);
    ((ushort4*)dst)[tid] = o;
}

// ---------------------------------------------------------------------------
// GEMM core: 128x128 tile, BK=32, global_load_lds staging, 4 waves 2x2 of 64x64
// ---------------------------------------------------------------------------
__device__ __forceinline__ void gemm_core(
    const unsigned short* __restrict__ A, const unsigned short* __restrict__ W,
    int m0, int n0, unsigned short* As, unsigned short* Bs,
    int tid, f32x4 acc[4][4])
{
    int lane = tid & 63, wid = tid >> 6;
    int fm = lane & 15, quad = lane >> 4;
    int wm = wid >> 1, wn = wid & 1;
    int r0 = tid >> 2, ko = (tid & 3) * 8;
    const unsigned short* Ap0 = A + (size_t)(m0 + r0) * DD + ko;
    const unsigned short* Ap1 = A + (size_t)(m0 + r0 + 64) * DD + ko;
    const unsigned short* Wp0 = W + (size_t)(n0 + r0) * DD + ko;
    const unsigned short* Wp1 = W + (size_t)(n0 + r0 + 64) * DD + ko;
    unsigned short* la0 = As + tid * 8;
    unsigned short* la1 = As + (256 + tid) * 8;
    unsigned short* lb0 = Bs + tid * 8;
    unsigned short* lb1 = Bs + (256 + tid) * 8;
    for (int k0 = 0; k0 < DD; k0 += 32) {
        GLD16(Ap0 + k0, la0);
        GLD16(Ap1 + k0, la1);
        GLD16(Wp0 + k0, lb0);
        GLD16(Wp1 + k0, lb1);
        __syncthreads();
        bf16x8 af[4], bf[4];
#pragma unroll
        for (int mt = 0; mt < 4; mt++)
            af[mt] = *(const bf16x8*)(As + (wm * 64 + mt * 16 + fm) * 32 + quad * 8);
#pragma unroll
        for (int nt = 0; nt < 4; nt++)
            bf[nt] = *(const bf16x8*)(Bs + (wn * 64 + nt * 16 + fm) * 32 + quad * 8);
#pragma unroll
        for (int mt = 0; mt < 4; mt++)
#pragma unroll
            for (int nt = 0; nt < 4; nt++)
                acc[mt][nt] = __builtin_amdgcn_mfma_f32_16x16x32_bf16(af[mt], bf[nt], acc[mt][nt], 0, 0, 0);
        __syncthreads();
    }
}

// ---------------------------------------------------------------------------
// K3: fused Q/K/V projection. grid (8, 80): y<48 Q (scaled by 1/8), y<64 K, else V.
// ---------------------------------------------------------------------------
__global__ __launch_bounds__(256) void qkv_gemm(
    const unsigned short* __restrict__ hq, const unsigned short* __restrict__ hx,
    const unsigned short* __restrict__ qwt, const unsigned short* __restrict__ kwt,
    const unsigned short* __restrict__ vwt,
    const float* __restrict__ q_b, const float* __restrict__ k_b,
    const float* __restrict__ v_b,
    unsigned short* __restrict__ Qb, unsigned short* __restrict__ Kb,
    unsigned short* __restrict__ VT)
{
    __shared__ __align__(16) unsigned short As[128 * 32];
    __shared__ __align__(16) unsigned short Bs[128 * 32];
    int ty = blockIdx.y, n0 = blockIdx.x * 128;
    const unsigned short *A, *W; const float* bias; int mode, m0;
    if (ty < 48) {
        m0 = ty * 128;
        int br = (m0 % 1536) >> 9;
        A = hq; W = qwt + (size_t)br * DD * DD; bias = q_b + (size_t)br * DD; mode = 0;
    } else if (ty < 64) {
        m0 = (ty - 48) * 128; A = hx; W = kwt; bias = k_b; mode = 1;
    } else {
        m0 = (ty - 64) * 128; A = hx; W = vwt; bias = v_b; mode = 2;
    }
    int tid = threadIdx.x, lane = tid & 63, wid = tid >> 6;
    int fm = lane & 15, quad = lane >> 4;
    int wm = wid >> 1, wn = wid & 1;
    f32x4 z = {0.f, 0.f, 0.f, 0.f};
    f32x4 acc[4][4];
#pragma unroll
    for (int mt = 0; mt < 4; mt++)
#pragma unroll
        for (int nt = 0; nt < 4; nt++) acc[mt][nt] = z;
    gemm_core(A, W, m0, n0, As, Bs, tid, acc);
#pragma unroll
    for (int mt = 0; mt < 4; mt++) {
#pragma unroll
        for (int nt = 0; nt < 4; nt++) {
            int c = n0 + wn * 64 + nt * 16 + fm;
            float bv = bias[c];
            int r0 = m0 + wm * 64 + mt * 16 + quad * 4;
            if (mode == 2) {
                int b = r0 >> 9, n = r0 & 511, hh = c >> 6, hd = c & 63;
                ushort4 st;
                st.x = f2bf(acc[mt][nt][0] + bv);
                st.y = f2bf(acc[mt][nt][1] + bv);
                st.z = f2bf(acc[mt][nt][2] + bv);
                st.w = f2bf(acc[mt][nt][3] + bv);
                *(ushort4*)(VT + (((size_t)(b * HH + hh)) * HD + hd) * NSEQ + n) = st;
            } else if (mode == 0) {
                // fold 1/sqrt(HD) = 0.125 into Q
#pragma unroll
                for (int reg = 0; reg < 4; reg++)
                    Qb[(size_t)(r0 + reg) * DD + c] = f2bf((acc[mt][nt][reg] + bv) * 0.125f);
            } else {
#pragma unroll
                for (int reg = 0; reg < 4; reg++)
                    Kb[(size_t)(r0 + reg) * DD + c] = f2bf(acc[mt][nt][reg] + bv);
            }
        }
    }
}

// ---------------------------------------------------------------------------
// K5: out projection, fp32 out remapped branch-major. grid (8, 48)
// ---------------------------------------------------------------------------
__global__ __launch_bounds__(256) void out_gemm(
    const unsigned short* __restrict__ Ain, const unsigned short* __restrict__ owt,
    const float* __restrict__ out_b, float* __restrict__ outp)
{
    __shared__ __align__(16) unsigned short As[128 * 32];
    __shared__ __align__(16) unsigned short Bs[128 * 32];
    int n0 = blockIdx.x * 128, m0 = blockIdx.y * 128;
    int br = (m0 % 1536) >> 9;
    const unsigned short* W = owt + (size_t)br * DD * DD;
    const float* bias = out_b + (size_t)br * DD;
    int tid = threadIdx.x, lane = tid & 63, wid = tid >> 6;
    int fm = lane & 15, quad = lane >> 4;
    int wm = wid >> 1, wn = wid & 1;
    f32x4 z = {0.f, 0.f, 0.f, 0.f};
    f32x4 acc[4][4];
#pragma unroll
    for (int mt = 0; mt < 4; mt++)
#pragma unroll
        for (int nt = 0; nt < 4; nt++) acc[mt][nt] = z;
    gemm_core(Ain, W, m0, n0, As, Bs, tid, acc);
#pragma unroll
    for (int mt = 0; mt < 4; mt++) {
#pragma unroll
        for (int nt = 0; nt < 4; nt++) {
            int c = n0 + wn * 64 + nt * 16 + fm;
            float bv = bias[c];
            int r0 = m0 + wm * 64 + mt * 16 + quad * 4;
            int b = r0 / 1536, t3 = r0 % 1536, t = t3 & 511;
#pragma unroll
            for (int reg = 0; reg < 4; reg++)
                outp[(size_t)br * (BB * TSEQ * DD) + (size_t)b * (TSEQ * DD)
                     + (size_t)(t + reg) * DD + c] = acc[mt][nt][reg] + bv;
        }
    }
}

// ---------------------------------------------------------------------------
// K4: attention, 32 queries/block, S^T in registers. grid (48, 64)
// mask folded into MFMA C-init; no max-subtraction (scores are O(1));
// single __syncthreads (P + redsum visibility).
// ---------------------------------------------------------------------------
__global__ __launch_bounds__(256) void attn_kernel(
    const unsigned short* __restrict__ Qb,
    const unsigned short* __restrict__ Kb,
    const unsigned short* __restrict__ VT,
    const unsigned char* __restrict__ mask,
    unsigned short* __restrict__ attn)
{
    __shared__ __align__(16) unsigned short P[32 * 520];
    __shared__ float redsum[128];
    int bh = blockIdx.y, b = bh >> 4, h = bh & 15;
    int m0 = blockIdx.x * 32;
    int tid = threadIdx.x, lane = tid & 63, w = tid >> 6;
    int fm = lane & 15, quad = lane >> 4;

    // per-wave mask bits for this wave's 128 keys (no LDS, no barrier)
    const unsigned char* mp = mask + (size_t)b * NSEQ + w * 128;
    unsigned long long mw0 = __ballot(mp[lane] != 0);
    unsigned long long mw1 = __ballot(mp[64 + lane] != 0);

    // phase 1: S^T = (K)(Q/8)^T with mask as C-init
    f32x4 acc[8][2];
#pragma unroll
    for (int mt = 0; mt < 8; mt++) {
        unsigned long long word = (mt >= 4) ? mw1 : mw0;
        int kb = (mt * 16 + quad * 4) & 63;
        f32x4 ini;
#pragma unroll
        for (int reg = 0; reg < 4; reg++)
            ini[reg] = ((word >> (kb + reg)) & 1ull) ? -1e30f : 0.f;
        acc[mt][0] = ini; acc[mt][1] = ini;
    }
    const unsigned short* Kp = Kb + ((size_t)(b * NSEQ + w * 128 + fm)) * DD + h * HD + quad * 8;
    const unsigned short* Qp = Qb + ((size_t)(b * 1536 + m0 + fm)) * DD + h * HD + quad * 8;
#pragma unroll
    for (int kk = 0; kk < 2; kk++) {
        bf16x8 bq0 = *(const bf16x8*)(Qp + kk * 32);
        bf16x8 bq1 = *(const bf16x8*)(Qp + (size_t)16 * DD + kk * 32);
#pragma unroll
        for (int mt = 0; mt < 8; mt++) {
            bf16x8 ak = *(const bf16x8*)(Kp + (size_t)mt * 16 * DD + kk * 32);
            acc[mt][0] = __builtin_amdgcn_mfma_f32_16x16x32_bf16(ak, bq0, acc[mt][0], 0, 0, 0);
            acc[mt][1] = __builtin_amdgcn_mfma_f32_16x16x32_bf16(ak, bq1, acc[mt][1], 0, 0, 0);
        }
    }

    // phase 2: e = exp(s) (no max shift), pack bf16 to LDS, column sums
    float s0 = 0.f, s1 = 0.f;
#pragma unroll
    for (int mt = 0; mt < 8; mt++) {
        float e00 = __expf(acc[mt][0][0]);
        float e01 = __expf(acc[mt][0][1]);
        float e02 = __expf(acc[mt][0][2]);
        float e03 = __expf(acc[mt][0][3]);
        float e10 = __expf(acc[mt][1][0]);
        float e11 = __expf(acc[mt][1][1]);
        float e12 = __expf(acc[mt][1][2]);
        float e13 = __expf(acc[mt][1][3]);
        s0 += (e00 + e01) + (e02 + e03);
        s1 += (e10 + e11) + (e12 + e13);
        uint2 p0, p1;
        p0.x = pkbf(e00, e01); p0.y = pkbf(e02, e03);
        p1.x = pkbf(e10, e11); p1.y = pkbf(e12, e13);
        int kb = w * 128 + mt * 16 + quad * 4;
        *(uint2*)(P + (size_t)fm * 520 + kb) = p0;
        *(uint2*)(P + (size_t)(16 + fm) * 520 + kb) = p1;
    }
    s0 += __shfl_xor(s0, 16, 64); s0 += __shfl_xor(s0, 32, 64);
    s1 += __shfl_xor(s1, 16, 64); s1 += __shfl_xor(s1, 32, 64);
    if (quad == 0) { redsum[w * 32 + fm] = s0; redsum[w * 32 + 16 + fm] = s1; }
    __syncthreads();

    // phase 3: O^T = V^T P
    float inv0 = 1.f / (redsum[fm] + redsum[32 + fm] + redsum[64 + fm] + redsum[96 + fm]);
    float inv1 = 1.f / (redsum[16 + fm] + redsum[48 + fm] + redsum[80 + fm] + redsum[112 + fm]);
    f32x4 z = {0.f, 0.f, 0.f, 0.f};
    f32x4 o0 = z, o1 = z;
    const unsigned short* Vp = VT + ((size_t)(bh * HD + w * 16 + fm)) * NSEQ + quad * 8;
    const unsigned short* Pp0 = P + (size_t)fm * 520 + quad * 8;
    const unsigned short* Pp1 = P + (size_t)(16 + fm) * 520 + quad * 8;
#pragma unroll
    for (int kk = 0; kk < 16; kk++) {
        bf16x8 av = *(const bf16x8*)(Vp + kk * 32);
        bf16x8 p0 = *(const bf16x8*)(Pp0 + kk * 32);
        bf16x8 p1 = *(const bf16x8*)(Pp1 + kk * 32);
        o0 = __builtin_amdgcn_mfma_f32_16x16x32_bf16(av, p0, o0, 0, 0, 0);
        o1 = __builtin_amdgcn_mfma_f32_16x16x32_bf16(av, p1, o1, 0, 0, 0);
    }
    ushort4 r0, r1;
    r0.x = f2bf(o0[0] * inv0); r0.y = f2bf(o0[1] * inv0);
    r0.z = f2bf(o0[2] * inv0); r0.w = f2bf(o0[3] * inv0);
    r1.x = f2bf(o1[0] * inv1); r1.y = f2bf(o1[1] * inv1);
    r1.z = f2bf(o1[2] * inv1); r1.w = f2bf(o1[3] * inv1);
    *(ushort4*)(attn + ((size_t)(b * 1536 + m0 + fm)) * DD + h * HD + w * 16 + quad * 4) = r0;
    *(ushort4*)(attn + ((size_t)(b * 1536 + m0 + 16 + fm)) * DD + h * HD + w * 16 + quad * 4) = r1;
}

// ---------------------------------------------------------------------------
extern "C" void kernel_launch(void* const* d_in, const int* in_sizes, int n_in,
                              void* d_out, int out_size, void* d_ws, size_t ws_size,
                              hipStream_t stream)
{
    const float* x1   = (const float*)d_in[0];
    const float* x2   = (const float*)d_in[1];
    const float* x3   = (const float*)d_in[2];
    const float* xf   = (const float*)d_in[3];
    const float* emb  = (const float*)d_in[4];
    const unsigned char* mask = (const unsigned char*)d_in[5];
    const float* adaln_w = (const float*)d_in[6];
    const float* adaln_b = (const float*)d_in[7];
    const float* xf_w = (const float*)d_in[8];
    const float* xf_b = (const float*)d_in[9];
    const float* q_w  = (const float*)d_in[10];
    const float* q_b  = (const float*)d_in[11];
    const float* k_w  = (const float*)d_in[12];
    const float* k_b  = (const float*)d_in[13];
    const float* v_w  = (const float*)d_in[14];
    const float* v_b  = (const float*)d_in[15];
    const float* out_w = (const float*)d_in[16];
    const float* out_b = (const float*)d_in[17];

    char* ws = (char*)d_ws;
    float* scaleB        = (float*)(ws + 0);
    float* shiftB        = (float*)(ws + 65536);
    unsigned short* hq   = (unsigned short*)(ws + 131072);     // 12.58 MB (reused for attn out)
    unsigned short* hx   = (unsigned short*)(ws + 12713984);   // 4.19 MB
    unsigned short* Qb   = (unsigned short*)(ws + 16908288);   // 12.58 MB
    unsigned short* Kb   = (unsigned short*)(ws + 29491200);   // 4.19 MB
    unsigned short* VT   = (unsigned short*)(ws + 33685504);   // 4.19 MB
    unsigned short* qwt  = (unsigned short*)(ws + 37879808);   // 6.29 MB
    unsigned short* kwt  = (unsigned short*)(ws + 44171264);   // 2.10 MB
    unsigned short* vwt  = (unsigned short*)(ws + 46268416);   // 2.10 MB
    unsigned short* owt  = (unsigned short*)(ws + 48365568);   // 6.29 MB (end ~54.7 MB)

    prep_kernel<<<2304, 256, 0, stream>>>(q_w, k_w, v_w, out_w, qwt, kwt, vwt, owt,
                                          emb, adaln_w, adaln_b, xf_w, xf_b,
                                          scaleB, shiftB);
    ln_mod_kernel<<<8192, 256, 0, stream>>>(x1, x2, x3, xf, scaleB, shiftB, hq, hx);
    qkv_gemm<<<dim3(8, 80), 256, 0, stream>>>(hq, hx, qwt, kwt, vwt, q_b, k_b, v_b,
                                              Qb, Kb, VT);
    attn_kernel<<<dim3(48, 64), 256, 0, stream>>>(Qb, Kb, VT, mask, hq);
    out_gemm<<<dim3(8, 48), 256, 0, stream>>>(hq, owt, out_b, (float*)d_out);
}

// Round 5
// 286.843 us; speedup vs baseline: 1.0992x; 1.0992x over previous
//
#include <hip/hip_runtime.h>
#include <hip/hip_bf16.h>
#include <stdint.h>

#define BB 4
#define TSEQ 512
#define NSEQ 512
#define DD 1024
#define EE 1024
#define HH 16
#define HD 64

typedef __attribute__((ext_vector_type(8))) short bf16x8;
typedef __attribute__((ext_vector_type(4))) float f32x4;

__device__ __forceinline__ unsigned short f2bf(float f) {
    union { float f; uint32_t u; } v; v.f = f;
    uint32_t u = v.u;
    uint32_t r = (u + 0x7fffu + ((u >> 16) & 1u)) >> 16;
    return (unsigned short)r;
}

__device__ __forceinline__ uint32_t pkbf(float a, float b) {
    __hip_bfloat162 t = __float22bfloat162_rn(float2{a, b});
    return *(uint32_t*)&t;
}

#define GLD16(gp, lp)                                                          \
    __builtin_amdgcn_global_load_lds(                                          \
        (const __attribute__((address_space(1))) unsigned int*)(gp),           \
        (__attribute__((address_space(3))) unsigned int*)(lp), 16, 0, 0)

// ---------------------------------------------------------------------------
// K1a: fused weight transpose+cvt for all 4 weight tensors (small LDS)
// grid (16 ktiles, 16 ntiles, 8): z 0-2 q_w, 3 k_w, 4 v_w, 5-7 out_w
// ---------------------------------------------------------------------------
__global__ __launch_bounds__(256) void tw_all_kernel(
    const float* __restrict__ q_w, const float* __restrict__ k_w,
    const float* __restrict__ v_w, const float* __restrict__ out_w,
    unsigned short* __restrict__ qwt, unsigned short* __restrict__ kwt,
    unsigned short* __restrict__ vwt, unsigned short* __restrict__ owt)
{
    __shared__ __align__(16) unsigned short Ts[64 * 72];
    int k0 = blockIdx.x * 64, n0 = blockIdx.y * 64;
    int z = blockIdx.z;
    const float* in; unsigned short* out;
    if (z < 3)       { in = q_w + (size_t)z * DD * DD;         out = qwt + (size_t)z * DD * DD; }
    else if (z == 3) { in = k_w;                               out = kwt; }
    else if (z == 4) { in = v_w;                               out = vwt; }
    else             { in = out_w + (size_t)(z - 5) * DD * DD; out = owt + (size_t)(z - 5) * DD * DD; }
    int tid = threadIdx.x;
    int r = tid >> 2, c0 = (tid & 3) * 16;
#pragma unroll
    for (int i = 0; i < 4; i++) {
        float4 v = *(const float4*)(in + (size_t)(k0 + r) * DD + n0 + c0 + i * 4);
        Ts[(c0 + i * 4 + 0) * 72 + r] = f2bf(v.x);
        Ts[(c0 + i * 4 + 1) * 72 + r] = f2bf(v.y);
        Ts[(c0 + i * 4 + 2) * 72 + r] = f2bf(v.z);
        Ts[(c0 + i * 4 + 3) * 72 + r] = f2bf(v.w);
    }
    __syncthreads();
#pragma unroll
    for (int i = 0; i < 2; i++) {
        int idx = i * 256 + tid;
        int row = idx >> 3, ko = (idx & 7) * 8;
        *(uint4*)(out + (size_t)(n0 + row) * DD + k0 + ko) =
            *(const uint4*)(Ts + row * 72 + ko);
    }
}

// ---------------------------------------------------------------------------
// K1b: adaln. grid (64 col-chunks of 32, 4 branches), block 256.
// ---------------------------------------------------------------------------
__global__ __launch_bounds__(256) void adaln_kernel(
    const float* __restrict__ emb,
    const float* __restrict__ adaln_w, const float* __restrict__ adaln_b,
    const float* __restrict__ xf_w, const float* __restrict__ xf_b,
    float* __restrict__ scaleB, float* __restrict__ shiftB)
{
    __shared__ __align__(16) float seT[EE][4];
    __shared__ float buf[128 * 33];
    int tid = threadIdx.x;
    int chunk = blockIdx.x, j = blockIdx.y;
#pragma unroll
    for (int b = 0; b < 4; b++) {
        float4 e4 = ((const float4*)(emb + (size_t)b * EE))[tid];
        seT[tid * 4 + 0][b] = e4.x / (1.f + __expf(-e4.x));
        seT[tid * 4 + 1][b] = e4.y / (1.f + __expf(-e4.y));
        seT[tid * 4 + 2][b] = e4.z / (1.f + __expf(-e4.z));
        seT[tid * 4 + 3][b] = e4.w / (1.f + __expf(-e4.w));
    }
    __syncthreads();
    const float* W    = (j < 3) ? (adaln_w + (size_t)j * EE * 2 * DD) : xf_w;
    const float* bias = (j < 3) ? (adaln_b + (size_t)j * 2 * DD) : xf_b;
    int eg = tid >> 3, cg = tid & 7;
    int c0 = chunk * 32 + cg * 4;
    const float* Wp = W + (size_t)(eg * 32) * (2 * DD) + c0;
    float4 a0 = {0,0,0,0}, a1 = {0,0,0,0}, a2 = {0,0,0,0}, a3 = {0,0,0,0};
#pragma unroll 8
    for (int e = 0; e < 32; e++) {
        float4 w = *(const float4*)(Wp + (size_t)e * (2 * DD));
        float4 s = *(const float4*)&seT[eg * 32 + e][0];
        a0.x += s.x * w.x; a0.y += s.x * w.y; a0.z += s.x * w.z; a0.w += s.x * w.w;
        a1.x += s.y * w.x; a1.y += s.y * w.y; a1.z += s.y * w.z; a1.w += s.y * w.w;
        a2.x += s.z * w.x; a2.y += s.z * w.y; a2.z += s.z * w.z; a2.w += s.z * w.w;
        a3.x += s.w * w.x; a3.y += s.w * w.y; a3.z += s.w * w.z; a3.w += s.w * w.w;
    }
    float accs[4][4] = {{a0.x,a0.y,a0.z,a0.w},{a1.x,a1.y,a1.z,a1.w},
                        {a2.x,a2.y,a2.z,a2.w},{a3.x,a3.y,a3.z,a3.w}};
#pragma unroll
    for (int b = 0; b < 4; b++)
#pragma unroll
        for (int i = 0; i < 4; i++)
            buf[(b * 32 + cg * 4 + i) * 33 + eg] = accs[b][i];
    __syncthreads();
    if (tid < 128) {
        int b = tid >> 5, cl = tid & 31;
        float s = 0.f;
#pragma unroll 8
        for (int e = 0; e < 32; e++) s += buf[(b * 32 + cl) * 33 + e];
        int c = chunk * 32 + cl;
        float v = s + bias[c];
        if (c < DD) scaleB[(size_t)(j * 4 + b) * DD + c] = v;
        else        shiftB[(size_t)(j * 4 + b) * DD + (c - DD)] = v;
    }
}

// ---------------------------------------------------------------------------
// K2: LayerNorm + modulate, cast bf16
// ---------------------------------------------------------------------------
__global__ __launch_bounds__(256) void ln_mod_kernel(
    const float* __restrict__ x1, const float* __restrict__ x2,
    const float* __restrict__ x3, const float* __restrict__ xf,
    const float* __restrict__ scaleB, const float* __restrict__ shiftB,
    unsigned short* __restrict__ hq, unsigned short* __restrict__ hx)
{
    __shared__ float rs[4], rq[4];
    int row = blockIdx.x, tid = threadIdx.x;
    const float* src; unsigned short* dst; int sb;
    if (row < 6144) {
        int b = row / 1536, t3 = row % 1536;
        int br = t3 >> 9, t = t3 & 511;
        const float* xs = (br == 0) ? x1 : ((br == 1) ? x2 : x3);
        src = xs + ((size_t)b * TSEQ + t) * DD;
        dst = hq + (size_t)row * DD;
        sb = br * 4 + b;
    } else {
        int idx = row - 6144;
        src = xf + (size_t)idx * DD;
        dst = hx + (size_t)idx * DD;
        sb = 12 + (idx >> 9);
    }
    float4 x = ((const float4*)src)[tid];
    float s = x.x + x.y + x.z + x.w;
    float q = x.x * x.x + x.y * x.y + x.z * x.z + x.w * x.w;
    for (int o = 1; o < 64; o <<= 1) { s += __shfl_xor(s, o, 64); q += __shfl_xor(q, o, 64); }
    int lane = tid & 63, wid = tid >> 6;
    if (lane == 0) { rs[wid] = s; rq[wid] = q; }
    __syncthreads();
    float S = rs[0] + rs[1] + rs[2] + rs[3];
    float Q = rq[0] + rq[1] + rq[2] + rq[3];
    float mu = S * (1.f / DD);
    float var = Q * (1.f / DD) - mu * mu;
    float rstd = rsqrtf(var + 1e-6f);
    float4 sc = ((const float4*)(scaleB + (size_t)sb * DD))[tid];
    float4 sh = ((const float4*)(shiftB + (size_t)sb * DD))[tid];
    ushort4 o;
    o.x = f2bf((x.x - mu) * rstd * (1.f + sc.x) + sh.x);
    o.y = f2bf((x.y - mu) * rstd * (1.f + sc.y) + sh.y);
    o.z = f2bf((x.z - mu) * rstd * (1.f + sc.z) + sh.z);
    o.w = f2bf((x.w - mu) * rstd * (1.f + sc.w) + sh.w);
    ((ushort4*)dst)[tid] = o;
}

// ---------------------------------------------------------------------------
// GEMM core: 128x128 tile, BK=32, global_load_lds staging, 4 waves 2x2 of 64x64
// ---------------------------------------------------------------------------
__device__ __forceinline__ void gemm_core(
    const unsigned short* __restrict__ A, const unsigned short* __restrict__ W,
    int m0, int n0, unsigned short* As, unsigned short* Bs,
    int tid, f32x4 acc[4][4])
{
    int lane = tid & 63, wid = tid >> 6;
    int fm = lane & 15, quad = lane >> 4;
    int wm = wid >> 1, wn = wid & 1;
    int r0 = tid >> 2, ko = (tid & 3) * 8;
    const unsigned short* Ap0 = A + (size_t)(m0 + r0) * DD + ko;
    const unsigned short* Ap1 = A + (size_t)(m0 + r0 + 64) * DD + ko;
    const unsigned short* Wp0 = W + (size_t)(n0 + r0) * DD + ko;
    const unsigned short* Wp1 = W + (size_t)(n0 + r0 + 64) * DD + ko;
    unsigned short* la0 = As + tid * 8;
    unsigned short* la1 = As + (256 + tid) * 8;
    unsigned short* lb0 = Bs + tid * 8;
    unsigned short* lb1 = Bs + (256 + tid) * 8;
    for (int k0 = 0; k0 < DD; k0 += 32) {
        GLD16(Ap0 + k0, la0);
        GLD16(Ap1 + k0, la1);
        GLD16(Wp0 + k0, lb0);
        GLD16(Wp1 + k0, lb1);
        __syncthreads();
        bf16x8 af[4], bf[4];
#pragma unroll
        for (int mt = 0; mt < 4; mt++)
            af[mt] = *(const bf16x8*)(As + (wm * 64 + mt * 16 + fm) * 32 + quad * 8);
#pragma unroll
        for (int nt = 0; nt < 4; nt++)
            bf[nt] = *(const bf16x8*)(Bs + (wn * 64 + nt * 16 + fm) * 32 + quad * 8);
#pragma unroll
        for (int mt = 0; mt < 4; mt++)
#pragma unroll
            for (int nt = 0; nt < 4; nt++)
                acc[mt][nt] = __builtin_amdgcn_mfma_f32_16x16x32_bf16(af[mt], bf[nt], acc[mt][nt], 0, 0, 0);
        __syncthreads();
    }
}

// ---------------------------------------------------------------------------
// K3: fused Q/K/V projection -> MFMA-fragment-packed outputs.
// Qpk[b][h][kk][t3][32], Kpk[b][h][kk][n][32], Vpk[b][h][c][hd][32]
// grid (8, 80): y<48 Q (scaled 1/8), y<64 K, else V.
// ---------------------------------------------------------------------------
__global__ __launch_bounds__(256) void qkv_gemm(
    const unsigned short* __restrict__ hq, const unsigned short* __restrict__ hx,
    const unsigned short* __restrict__ qwt, const unsigned short* __restrict__ kwt,
    const unsigned short* __restrict__ vwt,
    const float* __restrict__ q_b, const float* __restrict__ k_b,
    const float* __restrict__ v_b,
    unsigned short* __restrict__ Qpk, unsigned short* __restrict__ Kpk,
    unsigned short* __restrict__ Vpk)
{
    __shared__ __align__(16) unsigned short As[128 * 32];
    __shared__ __align__(16) unsigned short Bs[128 * 32];
    int ty = blockIdx.y, n0 = blockIdx.x * 128;
    const unsigned short *A, *W; const float* bias; int mode, m0;
    if (ty < 48) {
        m0 = ty * 128;
        int br = (m0 % 1536) >> 9;
        A = hq; W = qwt + (size_t)br * DD * DD; bias = q_b + (size_t)br * DD; mode = 0;
    } else if (ty < 64) {
        m0 = (ty - 48) * 128; A = hx; W = kwt; bias = k_b; mode = 1;
    } else {
        m0 = (ty - 64) * 128; A = hx; W = vwt; bias = v_b; mode = 2;
    }
    int tid = threadIdx.x, lane = tid & 63, wid = tid >> 6;
    int fm = lane & 15, quad = lane >> 4;
    int wm = wid >> 1, wn = wid & 1;
    f32x4 z = {0.f, 0.f, 0.f, 0.f};
    f32x4 acc[4][4];
#pragma unroll
    for (int mt = 0; mt < 4; mt++)
#pragma unroll
        for (int nt = 0; nt < 4; nt++) acc[mt][nt] = z;
    gemm_core(A, W, m0, n0, As, Bs, tid, acc);
#pragma unroll
    for (int mt = 0; mt < 4; mt++) {
#pragma unroll
        for (int nt = 0; nt < 4; nt++) {
            int c = n0 + wn * 64 + nt * 16 + fm;
            float bv = bias[c];
            int r0 = m0 + wm * 64 + mt * 16 + quad * 4;
            int h = c >> 6;
            if (mode == 0) {
                int b = r0 / 1536, t3 = r0 % 1536;
                int kk = (c >> 5) & 1, o = c & 31;
                size_t base = ((((size_t)(b * HH + h) * 2 + kk) * 1536) + t3) * 32 + o;
#pragma unroll
                for (int reg = 0; reg < 4; reg++)
                    Qpk[base + (size_t)reg * 32] = f2bf((acc[mt][nt][reg] + bv) * 0.125f);
            } else if (mode == 1) {
                int b = r0 >> 9, n = r0 & 511;
                int kk = (c >> 5) & 1, o = c & 31;
                size_t base = ((((size_t)(b * HH + h) * 2 + kk) * 512) + n) * 32 + o;
#pragma unroll
                for (int reg = 0; reg < 4; reg++)
                    Kpk[base + (size_t)reg * 32] = f2bf(acc[mt][nt][reg] + bv);
            } else {
                int b = r0 >> 9, n = r0 & 511;
                int hd = c & 63, cv = n >> 5, ko = n & 31;
                ushort4 st;
                st.x = f2bf(acc[mt][nt][0] + bv);
                st.y = f2bf(acc[mt][nt][1] + bv);
                st.z = f2bf(acc[mt][nt][2] + bv);
                st.w = f2bf(acc[mt][nt][3] + bv);
                *(ushort4*)(Vpk + ((((size_t)(b * HH + h) * 16 + cv) * 64) + hd) * 32 + ko) = st;
            }
        }
    }
}

// ---------------------------------------------------------------------------
// K5: out projection, fp32 out remapped branch-major. grid (8, 48)
// ---------------------------------------------------------------------------
__global__ __launch_bounds__(256) void out_gemm(
    const unsigned short* __restrict__ Ain, const unsigned short* __restrict__ owt,
    const float* __restrict__ out_b, float* __restrict__ outp)
{
    __shared__ __align__(16) unsigned short As[128 * 32];
    __shared__ __align__(16) unsigned short Bs[128 * 32];
    int n0 = blockIdx.x * 128, m0 = blockIdx.y * 128;
    int br = (m0 % 1536) >> 9;
    const unsigned short* W = owt + (size_t)br * DD * DD;
    const float* bias = out_b + (size_t)br * DD;
    int tid = threadIdx.x, lane = tid & 63, wid = tid >> 6;
    int fm = lane & 15, quad = lane >> 4;
    int wm = wid >> 1, wn = wid & 1;
    f32x4 z = {0.f, 0.f, 0.f, 0.f};
    f32x4 acc[4][4];
#pragma unroll
    for (int mt = 0; mt < 4; mt++)
#pragma unroll
        for (int nt = 0; nt < 4; nt++) acc[mt][nt] = z;
    gemm_core(Ain, W, m0, n0, As, Bs, tid, acc);
#pragma unroll
    for (int mt = 0; mt < 4; mt++) {
#pragma unroll
        for (int nt = 0; nt < 4; nt++) {
            int c = n0 + wn * 64 + nt * 16 + fm;
            float bv = bias[c];
            int r0 = m0 + wm * 64 + mt * 16 + quad * 4;
            int b = r0 / 1536, t3 = r0 % 1536, t = t3 & 511;
#pragma unroll
            for (int reg = 0; reg < 4; reg++)
                outp[(size_t)br * (BB * TSEQ * DD) + (size_t)b * (TSEQ * DD)
                     + (size_t)(t + reg) * DD + c] = acc[mt][nt][reg] + bv;
        }
    }
}

// ---------------------------------------------------------------------------
// K4: attention, 32 queries/block, packed-layout coalesced loads. grid (48, 64)
// ---------------------------------------------------------------------------
__global__ __launch_bounds__(256) void attn_kernel(
    const unsigned short* __restrict__ Qpk,
    const unsigned short* __restrict__ Kpk,
    const unsigned short* __restrict__ Vpk,
    const unsigned char* __restrict__ mask,
    unsigned short* __restrict__ attn)
{
    __shared__ __align__(16) unsigned short P[32 * 520];
    __shared__ float redsum[128];
    int bh = blockIdx.y, b = bh >> 4, h = bh & 15;
    int m0 = blockIdx.x * 32;
    int tid = threadIdx.x, lane = tid & 63, w = tid >> 6;
    int fm = lane & 15, quad = lane >> 4;

    const unsigned char* mp = mask + (size_t)b * NSEQ + w * 128;
    unsigned long long mw0 = __ballot(mp[lane] != 0);
    unsigned long long mw1 = __ballot(mp[64 + lane] != 0);

    // phase 1: S^T = K (Q/8)^T, mask as C-init, fully-coalesced fragment loads
    f32x4 acc[8][2];
#pragma unroll
    for (int mt = 0; mt < 8; mt++) {
        unsigned long long word = (mt >= 4) ? mw1 : mw0;
        int kb = (mt * 16 + quad * 4) & 63;
        f32x4 ini;
#pragma unroll
        for (int reg = 0; reg < 4; reg++)
            ini[reg] = ((word >> (kb + reg)) & 1ull) ? -1e30f : 0.f;
        acc[mt][0] = ini; acc[mt][1] = ini;
    }
    const unsigned short* Kbase = Kpk + (size_t)bh * 2 * 512 * 32 + quad * 8;
    const unsigned short* Qbase = Qpk + (size_t)bh * 2 * 1536 * 32 + quad * 8;
#pragma unroll
    for (int kk = 0; kk < 2; kk++) {
        bf16x8 bq0 = *(const bf16x8*)(Qbase + (size_t)(kk * 1536 + m0 + fm) * 32);
        bf16x8 bq1 = *(const bf16x8*)(Qbase + (size_t)(kk * 1536 + m0 + 16 + fm) * 32);
#pragma unroll
        for (int mt = 0; mt < 8; mt++) {
            bf16x8 ak = *(const bf16x8*)(Kbase + (size_t)(kk * 512 + w * 128 + mt * 16 + fm) * 32);
            acc[mt][0] = __builtin_amdgcn_mfma_f32_16x16x32_bf16(ak, bq0, acc[mt][0], 0, 0, 0);
            acc[mt][1] = __builtin_amdgcn_mfma_f32_16x16x32_bf16(ak, bq1, acc[mt][1], 0, 0, 0);
        }
    }

    // phase 2: e = exp(s), pack bf16 to LDS, column sums
    float s0 = 0.f, s1 = 0.f;
#pragma unroll
    for (int mt = 0; mt < 8; mt++) {
        float e00 = __expf(acc[mt][0][0]);
        float e01 = __expf(acc[mt][0][1]);
        float e02 = __expf(acc[mt][0][2]);
        float e03 = __expf(acc[mt][0][3]);
        float e10 = __expf(acc[mt][1][0]);
        float e11 = __expf(acc[mt][1][1]);
        float e12 = __expf(acc[mt][1][2]);
        float e13 = __expf(acc[mt][1][3]);
        s0 += (e00 + e01) + (e02 + e03);
        s1 += (e10 + e11) + (e12 + e13);
        uint2 p0, p1;
        p0.x = pkbf(e00, e01); p0.y = pkbf(e02, e03);
        p1.x = pkbf(e10, e11); p1.y = pkbf(e12, e13);
        int kb = w * 128 + mt * 16 + quad * 4;
        *(uint2*)(P + (size_t)fm * 520 + kb) = p0;
        *(uint2*)(P + (size_t)(16 + fm) * 520 + kb) = p1;
    }
    s0 += __shfl_xor(s0, 16, 64); s0 += __shfl_xor(s0, 32, 64);
    s1 += __shfl_xor(s1, 16, 64); s1 += __shfl_xor(s1, 32, 64);
    if (quad == 0) { redsum[w * 32 + fm] = s0; redsum[w * 32 + 16 + fm] = s1; }
    __syncthreads();

    // phase 3: O^T = V^T P (coalesced V fragments)
    float inv0 = 1.f / (redsum[fm] + redsum[32 + fm] + redsum[64 + fm] + redsum[96 + fm]);
    float inv1 = 1.f / (redsum[16 + fm] + redsum[48 + fm] + redsum[80 + fm] + redsum[112 + fm]);
    f32x4 z = {0.f, 0.f, 0.f, 0.f};
    f32x4 o0 = z, o1 = z;
    const unsigned short* Vbase = Vpk + (size_t)bh * 16 * 64 * 32 + (size_t)(w * 16 + fm) * 32 + quad * 8;
    const unsigned short* Pp0 = P + (size_t)fm * 520 + quad * 8;
    const unsigned short* Pp1 = P + (size_t)(16 + fm) * 520 + quad * 8;
#pragma unroll
    for (int kk = 0; kk < 16; kk++) {
        bf16x8 av = *(const bf16x8*)(Vbase + (size_t)kk * 64 * 32);
        bf16x8 p0 = *(const bf16x8*)(Pp0 + kk * 32);
        bf16x8 p1 = *(const bf16x8*)(Pp1 + kk * 32);
        o0 = __builtin_amdgcn_mfma_f32_16x16x32_bf16(av, p0, o0, 0, 0, 0);
        o1 = __builtin_amdgcn_mfma_f32_16x16x32_bf16(av, p1, o1, 0, 0, 0);
    }
    ushort4 r0, r1;
    r0.x = f2bf(o0[0] * inv0); r0.y = f2bf(o0[1] * inv0);
    r0.z = f2bf(o0[2] * inv0); r0.w = f2bf(o0[3] * inv0);
    r1.x = f2bf(o1[0] * inv1); r1.y = f2bf(o1[1] * inv1);
    r1.z = f2bf(o1[2] * inv1); r1.w = f2bf(o1[3] * inv1);
    *(ushort4*)(attn + ((size_t)(b * 1536 + m0 + fm)) * DD + h * HD + w * 16 + quad * 4) = r0;
    *(ushort4*)(attn + ((size_t)(b * 1536 + m0 + 16 + fm)) * DD + h * HD + w * 16 + quad * 4) = r1;
}

// ---------------------------------------------------------------------------
extern "C" void kernel_launch(void* const* d_in, const int* in_sizes, int n_in,
                              void* d_out, int out_size, void* d_ws, size_t ws_size,
                              hipStream_t stream)
{
    const float* x1   = (const float*)d_in[0];
    const float* x2   = (const float*)d_in[1];
    const float* x3   = (const float*)d_in[2];
    const float* xf   = (const float*)d_in[3];
    const float* emb  = (const float*)d_in[4];
    const unsigned char* mask = (const unsigned char*)d_in[5];
    const float* adaln_w = (const float*)d_in[6];
    const float* adaln_b = (const float*)d_in[7];
    const float* xf_w = (const float*)d_in[8];
    const float* xf_b = (const float*)d_in[9];
    const float* q_w  = (const float*)d_in[10];
    const float* q_b  = (const float*)d_in[11];
    const float* k_w  = (const float*)d_in[12];
    const float* k_b  = (const float*)d_in[13];
    const float* v_w  = (const float*)d_in[14];
    const float* v_b  = (const float*)d_in[15];
    const float* out_w = (const float*)d_in[16];
    const float* out_b = (const float*)d_in[17];

    char* ws = (char*)d_ws;
    float* scaleB        = (float*)(ws + 0);
    float* shiftB        = (float*)(ws + 65536);
    unsigned short* hq   = (unsigned short*)(ws + 131072);     // 12.58 MB (reused for attn out)
    unsigned short* hx   = (unsigned short*)(ws + 12713984);   // 4.19 MB
    unsigned short* Qpk  = (unsigned short*)(ws + 16908288);   // 12.58 MB
    unsigned short* Kpk  = (unsigned short*)(ws + 29491200);   // 4.19 MB
    unsigned short* Vpk  = (unsigned short*)(ws + 33685504);   // 4.19 MB
    unsigned short* qwt  = (unsigned short*)(ws + 37879808);   // 6.29 MB
    unsigned short* kwt  = (unsigned short*)(ws + 44171264);   // 2.10 MB
    unsigned short* vwt  = (unsigned short*)(ws + 46268416);   // 2.10 MB
    unsigned short* owt  = (unsigned short*)(ws + 48365568);   // 6.29 MB (end ~54.7 MB)

    tw_all_kernel<<<dim3(16, 16, 8), 256, 0, stream>>>(q_w, k_w, v_w, out_w,
                                                       qwt, kwt, vwt, owt);
    adaln_kernel<<<dim3(64, 4), 256, 0, stream>>>(emb, adaln_w, adaln_b, xf_w, xf_b,
                                                  scaleB, shiftB);
    ln_mod_kernel<<<8192, 256, 0, stream>>>(x1, x2, x3, xf, scaleB, shiftB, hq, hx);
    qkv_gemm<<<dim3(8, 80), 256, 0, stream>>>(hq, hx, qwt, kwt, vwt, q_b, k_b, v_b,
                                              Qpk, Kpk, Vpk);
    attn_kernel<<<dim3(48, 64), 256, 0, stream>>>(Qpk, Kpk, Vpk, mask, hq);
    out_gemm<<<dim3(8, 48), 256, 0, stream>>>(hq, owt, out_b, (float*)d_out);
}

// Round 6
// 283.764 us; speedup vs baseline: 1.1111x; 1.0109x over previous
//
#include <hip/hip_runtime.h>
#include <hip/hip_bf16.h>
#include <stdint.h>

#define BB 4
#define TSEQ 512
#define NSEQ 512
#define DD 1024
#define EE 1024
#define HH 16
#define HD 64

typedef __attribute__((ext_vector_type(8))) short bf16x8;
typedef __attribute__((ext_vector_type(4))) float f32x4;

__device__ __forceinline__ unsigned short f2bf(float f) {
    union { float f; uint32_t u; } v; v.f = f;
    uint32_t u = v.u;
    uint32_t r = (u + 0x7fffu + ((u >> 16) & 1u)) >> 16;
    return (unsigned short)r;
}

__device__ __forceinline__ uint32_t pkbf(float a, float b) {
    __hip_bfloat162 t = __float22bfloat162_rn(float2{a, b});
    return *(uint32_t*)&t;
}

#define GLD16(gp, lp)                                                          \
    __builtin_amdgcn_global_load_lds(                                          \
        (const __attribute__((address_space(1))) unsigned int*)(gp),           \
        (__attribute__((address_space(3))) unsigned int*)(lp), 16, 0, 0)

// ---------------------------------------------------------------------------
// K1a: fused weight transpose+cvt for all 4 weight tensors (small LDS)
// grid (16 ktiles, 16 ntiles, 8): z 0-2 q_w, 3 k_w, 4 v_w, 5-7 out_w
// ---------------------------------------------------------------------------
__global__ __launch_bounds__(256) void tw_all_kernel(
    const float* __restrict__ q_w, const float* __restrict__ k_w,
    const float* __restrict__ v_w, const float* __restrict__ out_w,
    unsigned short* __restrict__ qwt, unsigned short* __restrict__ kwt,
    unsigned short* __restrict__ vwt, unsigned short* __restrict__ owt)
{
    __shared__ __align__(16) unsigned short Ts[64 * 72];
    int k0 = blockIdx.x * 64, n0 = blockIdx.y * 64;
    int z = blockIdx.z;
    const float* in; unsigned short* out;
    if (z < 3)       { in = q_w + (size_t)z * DD * DD;         out = qwt + (size_t)z * DD * DD; }
    else if (z == 3) { in = k_w;                               out = kwt; }
    else if (z == 4) { in = v_w;                               out = vwt; }
    else             { in = out_w + (size_t)(z - 5) * DD * DD; out = owt + (size_t)(z - 5) * DD * DD; }
    int tid = threadIdx.x;
    int r = tid >> 2, c0 = (tid & 3) * 16;
#pragma unroll
    for (int i = 0; i < 4; i++) {
        float4 v = *(const float4*)(in + (size_t)(k0 + r) * DD + n0 + c0 + i * 4);
        Ts[(c0 + i * 4 + 0) * 72 + r] = f2bf(v.x);
        Ts[(c0 + i * 4 + 1) * 72 + r] = f2bf(v.y);
        Ts[(c0 + i * 4 + 2) * 72 + r] = f2bf(v.z);
        Ts[(c0 + i * 4 + 3) * 72 + r] = f2bf(v.w);
    }
    __syncthreads();
#pragma unroll
    for (int i = 0; i < 2; i++) {
        int idx = i * 256 + tid;
        int row = idx >> 3, ko = (idx & 7) * 8;
        *(uint4*)(out + (size_t)(n0 + row) * DD + k0 + ko) =
            *(const uint4*)(Ts + row * 72 + ko);
    }
}

// ---------------------------------------------------------------------------
// K1b: adaln. grid (64 col-chunks of 32, 4 branches), block 256.
// ---------------------------------------------------------------------------
__global__ __launch_bounds__(256) void adaln_kernel(
    const float* __restrict__ emb,
    const float* __restrict__ adaln_w, const float* __restrict__ adaln_b,
    const float* __restrict__ xf_w, const float* __restrict__ xf_b,
    float* __restrict__ scaleB, float* __restrict__ shiftB)
{
    __shared__ __align__(16) float seT[EE][4];
    __shared__ float buf[128 * 33];
    int tid = threadIdx.x;
    int chunk = blockIdx.x, j = blockIdx.y;
#pragma unroll
    for (int b = 0; b < 4; b++) {
        float4 e4 = ((const float4*)(emb + (size_t)b * EE))[tid];
        seT[tid * 4 + 0][b] = e4.x / (1.f + __expf(-e4.x));
        seT[tid * 4 + 1][b] = e4.y / (1.f + __expf(-e4.y));
        seT[tid * 4 + 2][b] = e4.z / (1.f + __expf(-e4.z));
        seT[tid * 4 + 3][b] = e4.w / (1.f + __expf(-e4.w));
    }
    __syncthreads();
    const float* W    = (j < 3) ? (adaln_w + (size_t)j * EE * 2 * DD) : xf_w;
    const float* bias = (j < 3) ? (adaln_b + (size_t)j * 2 * DD) : xf_b;
    int eg = tid >> 3, cg = tid & 7;
    int c0 = chunk * 32 + cg * 4;
    const float* Wp = W + (size_t)(eg * 32) * (2 * DD) + c0;
    float4 a0 = {0,0,0,0}, a1 = {0,0,0,0}, a2 = {0,0,0,0}, a3 = {0,0,0,0};
#pragma unroll 8
    for (int e = 0; e < 32; e++) {
        float4 w = *(const float4*)(Wp + (size_t)e * (2 * DD));
        float4 s = *(const float4*)&seT[eg * 32 + e][0];
        a0.x += s.x * w.x; a0.y += s.x * w.y; a0.z += s.x * w.z; a0.w += s.x * w.w;
        a1.x += s.y * w.x; a1.y += s.y * w.y; a1.z += s.y * w.z; a1.w += s.y * w.w;
        a2.x += s.z * w.x; a2.y += s.z * w.y; a2.z += s.z * w.z; a2.w += s.z * w.w;
        a3.x += s.w * w.x; a3.y += s.w * w.y; a3.z += s.w * w.z; a3.w += s.w * w.w;
    }
    float accs[4][4] = {{a0.x,a0.y,a0.z,a0.w},{a1.x,a1.y,a1.z,a1.w},
                        {a2.x,a2.y,a2.z,a2.w},{a3.x,a3.y,a3.z,a3.w}};
#pragma unroll
    for (int b = 0; b < 4; b++)
#pragma unroll
        for (int i = 0; i < 4; i++)
            buf[(b * 32 + cg * 4 + i) * 33 + eg] = accs[b][i];
    __syncthreads();
    if (tid < 128) {
        int b = tid >> 5, cl = tid & 31;
        float s = 0.f;
#pragma unroll 8
        for (int e = 0; e < 32; e++) s += buf[(b * 32 + cl) * 33 + e];
        int c = chunk * 32 + cl;
        float v = s + bias[c];
        if (c < DD) scaleB[(size_t)(j * 4 + b) * DD + c] = v;
        else        shiftB[(size_t)(j * 4 + b) * DD + (c - DD)] = v;
    }
}

// ---------------------------------------------------------------------------
// K2: LayerNorm + modulate, cast bf16
// ---------------------------------------------------------------------------
__global__ __launch_bounds__(256) void ln_mod_kernel(
    const float* __restrict__ x1, const float* __restrict__ x2,
    const float* __restrict__ x3, const float* __restrict__ xf,
    const float* __restrict__ scaleB, const float* __restrict__ shiftB,
    unsigned short* __restrict__ hq, unsigned short* __restrict__ hx)
{
    __shared__ float rs[4], rq[4];
    int row = blockIdx.x, tid = threadIdx.x;
    const float* src; unsigned short* dst; int sb;
    if (row < 6144) {
        int b = row / 1536, t3 = row % 1536;
        int br = t3 >> 9, t = t3 & 511;
        const float* xs = (br == 0) ? x1 : ((br == 1) ? x2 : x3);
        src = xs + ((size_t)b * TSEQ + t) * DD;
        dst = hq + (size_t)row * DD;
        sb = br * 4 + b;
    } else {
        int idx = row - 6144;
        src = xf + (size_t)idx * DD;
        dst = hx + (size_t)idx * DD;
        sb = 12 + (idx >> 9);
    }
    float4 x = ((const float4*)src)[tid];
    float s = x.x + x.y + x.z + x.w;
    float q = x.x * x.x + x.y * x.y + x.z * x.z + x.w * x.w;
    for (int o = 1; o < 64; o <<= 1) { s += __shfl_xor(s, o, 64); q += __shfl_xor(q, o, 64); }
    int lane = tid & 63, wid = tid >> 6;
    if (lane == 0) { rs[wid] = s; rq[wid] = q; }
    __syncthreads();
    float S = rs[0] + rs[1] + rs[2] + rs[3];
    float Q = rq[0] + rq[1] + rq[2] + rq[3];
    float mu = S * (1.f / DD);
    float var = Q * (1.f / DD) - mu * mu;
    float rstd = rsqrtf(var + 1e-6f);
    float4 sc = ((const float4*)(scaleB + (size_t)sb * DD))[tid];
    float4 sh = ((const float4*)(shiftB + (size_t)sb * DD))[tid];
    ushort4 o;
    o.x = f2bf((x.x - mu) * rstd * (1.f + sc.x) + sh.x);
    o.y = f2bf((x.y - mu) * rstd * (1.f + sc.y) + sh.y);
    o.z = f2bf((x.z - mu) * rstd * (1.f + sc.z) + sh.z);
    o.w = f2bf((x.w - mu) * rstd * (1.f + sc.w) + sh.w);
    ((ushort4*)dst)[tid] = o;
}

// ---------------------------------------------------------------------------
// GEMM core: 128x128 tile, BK=32, global_load_lds staging, 4 waves 2x2 of 64x64
// XOR chunk swizzle: thread stages global k-chunk (tid&3)^(row&3) so fragment
// reads hit 4 distinct bank groups (4-way) instead of 2 (8-way).
// ---------------------------------------------------------------------------
__device__ __forceinline__ void gemm_core(
    const unsigned short* __restrict__ A, const unsigned short* __restrict__ W,
    int m0, int n0, unsigned short* As, unsigned short* Bs,
    int tid, f32x4 acc[4][4])
{
    int lane = tid & 63, wid = tid >> 6;
    int fm = lane & 15, quad = lane >> 4;
    int wm = wid >> 1, wn = wid & 1;
    int r0 = tid >> 2;
    int ko = (((tid & 3) ^ (r0 & 3))) * 8;   // swizzled global k-chunk
    const unsigned short* Ap0 = A + (size_t)(m0 + r0) * DD + ko;
    const unsigned short* Ap1 = A + (size_t)(m0 + r0 + 64) * DD + ko;
    const unsigned short* Wp0 = W + (size_t)(n0 + r0) * DD + ko;
    const unsigned short* Wp1 = W + (size_t)(n0 + r0 + 64) * DD + ko;
    unsigned short* la0 = As + tid * 8;
    unsigned short* la1 = As + (256 + tid) * 8;
    unsigned short* lb0 = Bs + tid * 8;
    unsigned short* lb1 = Bs + (256 + tid) * 8;
    int sqa = (quad ^ (fm & 3)) * 8;         // swizzled LDS chunk position
    for (int k0 = 0; k0 < DD; k0 += 32) {
        GLD16(Ap0 + k0, la0);
        GLD16(Ap1 + k0, la1);
        GLD16(Wp0 + k0, lb0);
        GLD16(Wp1 + k0, lb1);
        __syncthreads();
        bf16x8 af[4], bf[4];
#pragma unroll
        for (int mt = 0; mt < 4; mt++)
            af[mt] = *(const bf16x8*)(As + (wm * 64 + mt * 16 + fm) * 32 + sqa);
#pragma unroll
        for (int nt = 0; nt < 4; nt++)
            bf[nt] = *(const bf16x8*)(Bs + (wn * 64 + nt * 16 + fm) * 32 + sqa);
#pragma unroll
        for (int mt = 0; mt < 4; mt++)
#pragma unroll
            for (int nt = 0; nt < 4; nt++)
                acc[mt][nt] = __builtin_amdgcn_mfma_f32_16x16x32_bf16(af[mt], bf[nt], acc[mt][nt], 0, 0, 0);
        __syncthreads();
    }
}

// ---------------------------------------------------------------------------
// K3: fused Q/K/V projection -> MFMA-fragment-packed outputs.
// flat grid 640: m-tile = id % 80 (XCD-affine: all 8 n-blocks of an m-tile
// share id%8), n-tile = id / 80.
// ---------------------------------------------------------------------------
__global__ __launch_bounds__(256) void qkv_gemm(
    const unsigned short* __restrict__ hq, const unsigned short* __restrict__ hx,
    const unsigned short* __restrict__ qwt, const unsigned short* __restrict__ kwt,
    const unsigned short* __restrict__ vwt,
    const float* __restrict__ q_b, const float* __restrict__ k_b,
    const float* __restrict__ v_b,
    unsigned short* __restrict__ Qpk, unsigned short* __restrict__ Kpk,
    unsigned short* __restrict__ Vpk)
{
    __shared__ __align__(16) unsigned short As[128 * 32];
    __shared__ __align__(16) unsigned short Bs[128 * 32];
    int id = blockIdx.x;
    int ty = id % 80, n0 = (id / 80) * 128;
    const unsigned short *A, *W; const float* bias; int mode, m0;
    if (ty < 48) {
        m0 = ty * 128;
        int br = (m0 % 1536) >> 9;
        A = hq; W = qwt + (size_t)br * DD * DD; bias = q_b + (size_t)br * DD; mode = 0;
    } else if (ty < 64) {
        m0 = (ty - 48) * 128; A = hx; W = kwt; bias = k_b; mode = 1;
    } else {
        m0 = (ty - 64) * 128; A = hx; W = vwt; bias = v_b; mode = 2;
    }
    int tid = threadIdx.x, lane = tid & 63, wid = tid >> 6;
    int fm = lane & 15, quad = lane >> 4;
    int wm = wid >> 1, wn = wid & 1;
    f32x4 z = {0.f, 0.f, 0.f, 0.f};
    f32x4 acc[4][4];
#pragma unroll
    for (int mt = 0; mt < 4; mt++)
#pragma unroll
        for (int nt = 0; nt < 4; nt++) acc[mt][nt] = z;
    gemm_core(A, W, m0, n0, As, Bs, tid, acc);
#pragma unroll
    for (int mt = 0; mt < 4; mt++) {
#pragma unroll
        for (int nt = 0; nt < 4; nt++) {
            int c = n0 + wn * 64 + nt * 16 + fm;
            float bv = bias[c];
            int r0 = m0 + wm * 64 + mt * 16 + quad * 4;
            int h = c >> 6;
            if (mode == 0) {
                int b = r0 / 1536, t3 = r0 % 1536;
                int kk = (c >> 5) & 1, o = c & 31;
                size_t base = ((((size_t)(b * HH + h) * 2 + kk) * 1536) + t3) * 32 + o;
#pragma unroll
                for (int reg = 0; reg < 4; reg++)
                    Qpk[base + (size_t)reg * 32] = f2bf((acc[mt][nt][reg] + bv) * 0.125f);
            } else if (mode == 1) {
                int b = r0 >> 9, n = r0 & 511;
                int kk = (c >> 5) & 1, o = c & 31;
                size_t base = ((((size_t)(b * HH + h) * 2 + kk) * 512) + n) * 32 + o;
#pragma unroll
                for (int reg = 0; reg < 4; reg++)
                    Kpk[base + (size_t)reg * 32] = f2bf(acc[mt][nt][reg] + bv);
            } else {
                int b = r0 >> 9, n = r0 & 511;
                int hd = c & 63, cv = n >> 5, ko = n & 31;
                ushort4 st;
                st.x = f2bf(acc[mt][nt][0] + bv);
                st.y = f2bf(acc[mt][nt][1] + bv);
                st.z = f2bf(acc[mt][nt][2] + bv);
                st.w = f2bf(acc[mt][nt][3] + bv);
                *(ushort4*)(Vpk + ((((size_t)(b * HH + h) * 16 + cv) * 64) + hd) * 32 + ko) = st;
            }
        }
    }
}

// ---------------------------------------------------------------------------
// K5: out projection, fp32 out remapped branch-major. flat grid 384:
// m = id % 48 (XCD-affine), n = id / 48.
// ---------------------------------------------------------------------------
__global__ __launch_bounds__(256) void out_gemm(
    const unsigned short* __restrict__ Ain, const unsigned short* __restrict__ owt,
    const float* __restrict__ out_b, float* __restrict__ outp)
{
    __shared__ __align__(16) unsigned short As[128 * 32];
    __shared__ __align__(16) unsigned short Bs[128 * 32];
    int id = blockIdx.x;
    int m0 = (id % 48) * 128, n0 = (id / 48) * 128;
    int br = (m0 % 1536) >> 9;
    const unsigned short* W = owt + (size_t)br * DD * DD;
    const float* bias = out_b + (size_t)br * DD;
    int tid = threadIdx.x, lane = tid & 63, wid = tid >> 6;
    int fm = lane & 15, quad = lane >> 4;
    int wm = wid >> 1, wn = wid & 1;
    f32x4 z = {0.f, 0.f, 0.f, 0.f};
    f32x4 acc[4][4];
#pragma unroll
    for (int mt = 0; mt < 4; mt++)
#pragma unroll
        for (int nt = 0; nt < 4; nt++) acc[mt][nt] = z;
    gemm_core(Ain, W, m0, n0, As, Bs, tid, acc);
#pragma unroll
    for (int mt = 0; mt < 4; mt++) {
#pragma unroll
        for (int nt = 0; nt < 4; nt++) {
            int c = n0 + wn * 64 + nt * 16 + fm;
            float bv = bias[c];
            int r0 = m0 + wm * 64 + mt * 16 + quad * 4;
            int b = r0 / 1536, t3 = r0 % 1536, t = t3 & 511;
#pragma unroll
            for (int reg = 0; reg < 4; reg++)
                outp[(size_t)br * (BB * TSEQ * DD) + (size_t)b * (TSEQ * DD)
                     + (size_t)(t + reg) * DD + c] = acc[mt][nt][reg] + bv;
        }
    }
}

// ---------------------------------------------------------------------------
// K4: attention, 32 queries/block, packed-layout coalesced loads. grid (48, 64)
// ---------------------------------------------------------------------------
__global__ __launch_bounds__(256) void attn_kernel(
    const unsigned short* __restrict__ Qpk,
    const unsigned short* __restrict__ Kpk,
    const unsigned short* __restrict__ Vpk,
    const unsigned char* __restrict__ mask,
    unsigned short* __restrict__ attn)
{
    __shared__ __align__(16) unsigned short P[32 * 520];
    __shared__ float redsum[128];
    int bh = blockIdx.y, b = bh >> 4, h = bh & 15;
    int m0 = blockIdx.x * 32;
    int tid = threadIdx.x, lane = tid & 63, w = tid >> 6;
    int fm = lane & 15, quad = lane >> 4;

    const unsigned char* mp = mask + (size_t)b * NSEQ + w * 128;
    unsigned long long mw0 = __ballot(mp[lane] != 0);
    unsigned long long mw1 = __ballot(mp[64 + lane] != 0);

    // phase 1: S^T = K (Q/8)^T, mask as C-init, fully-coalesced fragment loads
    f32x4 acc[8][2];
#pragma unroll
    for (int mt = 0; mt < 8; mt++) {
        unsigned long long word = (mt >= 4) ? mw1 : mw0;
        int kb = (mt * 16 + quad * 4) & 63;
        f32x4 ini;
#pragma unroll
        for (int reg = 0; reg < 4; reg++)
            ini[reg] = ((word >> (kb + reg)) & 1ull) ? -1e30f : 0.f;
        acc[mt][0] = ini; acc[mt][1] = ini;
    }
    const unsigned short* Kbase = Kpk + (size_t)bh * 2 * 512 * 32 + quad * 8;
    const unsigned short* Qbase = Qpk + (size_t)bh * 2 * 1536 * 32 + quad * 8;
#pragma unroll
    for (int kk = 0; kk < 2; kk++) {
        bf16x8 bq0 = *(const bf16x8*)(Qbase + (size_t)(kk * 1536 + m0 + fm) * 32);
        bf16x8 bq1 = *(const bf16x8*)(Qbase + (size_t)(kk * 1536 + m0 + 16 + fm) * 32);
#pragma unroll
        for (int mt = 0; mt < 8; mt++) {
            bf16x8 ak = *(const bf16x8*)(Kbase + (size_t)(kk * 512 + w * 128 + mt * 16 + fm) * 32);
            acc[mt][0] = __builtin_amdgcn_mfma_f32_16x16x32_bf16(ak, bq0, acc[mt][0], 0, 0, 0);
            acc[mt][1] = __builtin_amdgcn_mfma_f32_16x16x32_bf16(ak, bq1, acc[mt][1], 0, 0, 0);
        }
    }

    // phase 2: e = exp(s), pack bf16 to LDS, column sums
    float s0 = 0.f, s1 = 0.f;
#pragma unroll
    for (int mt = 0; mt < 8; mt++) {
        float e00 = __expf(acc[mt][0][0]);
        float e01 = __expf(acc[mt][0][1]);
        float e02 = __expf(acc[mt][0][2]);
        float e03 = __expf(acc[mt][0][3]);
        float e10 = __expf(acc[mt][1][0]);
        float e11 = __expf(acc[mt][1][1]);
        float e12 = __expf(acc[mt][1][2]);
        float e13 = __expf(acc[mt][1][3]);
        s0 += (e00 + e01) + (e02 + e03);
        s1 += (e10 + e11) + (e12 + e13);
        uint2 p0, p1;
        p0.x = pkbf(e00, e01); p0.y = pkbf(e02, e03);
        p1.x = pkbf(e10, e11); p1.y = pkbf(e12, e13);
        int kb = w * 128 + mt * 16 + quad * 4;
        *(uint2*)(P + (size_t)fm * 520 + kb) = p0;
        *(uint2*)(P + (size_t)(16 + fm) * 520 + kb) = p1;
    }
    s0 += __shfl_xor(s0, 16, 64); s0 += __shfl_xor(s0, 32, 64);
    s1 += __shfl_xor(s1, 16, 64); s1 += __shfl_xor(s1, 32, 64);
    if (quad == 0) { redsum[w * 32 + fm] = s0; redsum[w * 32 + 16 + fm] = s1; }
    __syncthreads();

    // phase 3: O^T = V^T P (coalesced V fragments)
    float inv0 = 1.f / (redsum[fm] + redsum[32 + fm] + redsum[64 + fm] + redsum[96 + fm]);
    float inv1 = 1.f / (redsum[16 + fm] + redsum[48 + fm] + redsum[80 + fm] + redsum[112 + fm]);
    f32x4 z = {0.f, 0.f, 0.f, 0.f};
    f32x4 o0 = z, o1 = z;
    const unsigned short* Vbase = Vpk + (size_t)bh * 16 * 64 * 32 + (size_t)(w * 16 + fm) * 32 + quad * 8;
    const unsigned short* Pp0 = P + (size_t)fm * 520 + quad * 8;
    const unsigned short* Pp1 = P + (size_t)(16 + fm) * 520 + quad * 8;
#pragma unroll
    for (int kk = 0; kk < 16; kk++) {
        bf16x8 av = *(const bf16x8*)(Vbase + (size_t)kk * 64 * 32);
        bf16x8 p0 = *(const bf16x8*)(Pp0 + kk * 32);
        bf16x8 p1 = *(const bf16x8*)(Pp1 + kk * 32);
        o0 = __builtin_amdgcn_mfma_f32_16x16x32_bf16(av, p0, o0, 0, 0, 0);
        o1 = __builtin_amdgcn_mfma_f32_16x16x32_bf16(av, p1, o1, 0, 0, 0);
    }
    ushort4 r0, r1;
    r0.x = f2bf(o0[0] * inv0); r0.y = f2bf(o0[1] * inv0);
    r0.z = f2bf(o0[2] * inv0); r0.w = f2bf(o0[3] * inv0);
    r1.x = f2bf(o1[0] * inv1); r1.y = f2bf(o1[1] * inv1);
    r1.z = f2bf(o1[2] * inv1); r1.w = f2bf(o1[3] * inv1);
    *(ushort4*)(attn + ((size_t)(b * 1536 + m0 + fm)) * DD + h * HD + w * 16 + quad * 4) = r0;
    *(ushort4*)(attn + ((size_t)(b * 1536 + m0 + 16 + fm)) * DD + h * HD + w * 16 + quad * 4) = r1;
}

// ---------------------------------------------------------------------------
extern "C" void kernel_launch(void* const* d_in, const int* in_sizes, int n_in,
                              void* d_out, int out_size, void* d_ws, size_t ws_size,
                              hipStream_t stream)
{
    const float* x1   = (const float*)d_in[0];
    const float* x2   = (const float*)d_in[1];
    const float* x3   = (const float*)d_in[2];
    const float* xf   = (const float*)d_in[3];
    const float* emb  = (const float*)d_in[4];
    const unsigned char* mask = (const unsigned char*)d_in[5];
    const float* adaln_w = (const float*)d_in[6];
    const float* adaln_b = (const float*)d_in[7];
    const float* xf_w = (const float*)d_in[8];
    const float* xf_b = (const float*)d_in[9];
    const float* q_w  = (const float*)d_in[10];
    const float* q_b  = (const float*)d_in[11];
    const float* k_w  = (const float*)d_in[12];
    const float* k_b  = (const float*)d_in[13];
    const float* v_w  = (const float*)d_in[14];
    const float* v_b  = (const float*)d_in[15];
    const float* out_w = (const float*)d_in[16];
    const float* out_b = (const float*)d_in[17];

    char* ws = (char*)d_ws;
    float* scaleB        = (float*)(ws + 0);
    float* shiftB        = (float*)(ws + 65536);
    unsigned short* hq   = (unsigned short*)(ws + 131072);     // 12.58 MB (reused for attn out)
    unsigned short* hx   = (unsigned short*)(ws + 12713984);   // 4.19 MB
    unsigned short* Qpk  = (unsigned short*)(ws + 16908288);   // 12.58 MB
    unsigned short* Kpk  = (unsigned short*)(ws + 29491200);   // 4.19 MB
    unsigned short* Vpk  = (unsigned short*)(ws + 33685504);   // 4.19 MB
    unsigned short* qwt  = (unsigned short*)(ws + 37879808);   // 6.29 MB
    unsigned short* kwt  = (unsigned short*)(ws + 44171264);   // 2.10 MB
    unsigned short* vwt  = (unsigned short*)(ws + 46268416);   // 2.10 MB
    unsigned short* owt  = (unsigned short*)(ws + 48365568);   // 6.29 MB (end ~54.7 MB)

    tw_all_kernel<<<dim3(16, 16, 8), 256, 0, stream>>>(q_w, k_w, v_w, out_w,
                                                       qwt, kwt, vwt, owt);
    adaln_kernel<<<dim3(64, 4), 256, 0, stream>>>(emb, adaln_w, adaln_b, xf_w, xf_b,
                                                  scaleB, shiftB);
    ln_mod_kernel<<<8192, 256, 0, stream>>>(x1, x2, x3, xf, scaleB, shiftB, hq, hx);
    qkv_gemm<<<640, 256, 0, stream>>>(hq, hx, qwt, kwt, vwt, q_b, k_b, v_b,
                                      Qpk, Kpk, Vpk);
    attn_kernel<<<dim3(48, 64), 256, 0, stream>>>(Qpk, Kpk, Vpk, mask, hq);
    out_gemm<<<384, 256, 0, stream>>>(hq, owt, out_b, (float*)d_out);
}

// Round 7
// 273.704 us; speedup vs baseline: 1.1520x; 1.0368x over previous
//
#include <hip/hip_runtime.h>
#include <hip/hip_bf16.h>
#include <stdint.h>

#define BB 4
#define TSEQ 512
#define NSEQ 512
#define DD 1024
#define EE 1024
#define HH 16
#define HD 64

typedef __attribute__((ext_vector_type(8))) short bf16x8;
typedef __attribute__((ext_vector_type(4))) float f32x4;

__device__ __forceinline__ unsigned short f2bf(float f) {
    union { float f; uint32_t u; } v; v.f = f;
    uint32_t u = v.u;
    uint32_t r = (u + 0x7fffu + ((u >> 16) & 1u)) >> 16;
    return (unsigned short)r;
}

__device__ __forceinline__ uint32_t pkbf(float a, float b) {
    __hip_bfloat162 t = __float22bfloat162_rn(float2{a, b});
    return *(uint32_t*)&t;
}

#define GLD16(gp, lp)                                                          \
    __builtin_amdgcn_global_load_lds(                                          \
        (const __attribute__((address_space(1))) unsigned int*)(gp),           \
        (__attribute__((address_space(3))) unsigned int*)(lp), 16, 0, 0)

// ---------------------------------------------------------------------------
// K1a: fused weight transpose+cvt for all 4 weight tensors (small LDS)
// grid (16 ktiles, 16 ntiles, 8): z 0-2 q_w, 3 k_w, 4 v_w, 5-7 out_w
// ---------------------------------------------------------------------------
__global__ __launch_bounds__(256) void tw_all_kernel(
    const float* __restrict__ q_w, const float* __restrict__ k_w,
    const float* __restrict__ v_w, const float* __restrict__ out_w,
    unsigned short* __restrict__ qwt, unsigned short* __restrict__ kwt,
    unsigned short* __restrict__ vwt, unsigned short* __restrict__ owt)
{
    __shared__ __align__(16) unsigned short Ts[64 * 72];
    int k0 = blockIdx.x * 64, n0 = blockIdx.y * 64;
    int z = blockIdx.z;
    const float* in; unsigned short* out;
    if (z < 3)       { in = q_w + (size_t)z * DD * DD;         out = qwt + (size_t)z * DD * DD; }
    else if (z == 3) { in = k_w;                               out = kwt; }
    else if (z == 4) { in = v_w;                               out = vwt; }
    else             { in = out_w + (size_t)(z - 5) * DD * DD; out = owt + (size_t)(z - 5) * DD * DD; }
    int tid = threadIdx.x;
    int r = tid >> 2, c0 = (tid & 3) * 16;
#pragma unroll
    for (int i = 0; i < 4; i++) {
        float4 v = *(const float4*)(in + (size_t)(k0 + r) * DD + n0 + c0 + i * 4);
        Ts[(c0 + i * 4 + 0) * 72 + r] = f2bf(v.x);
        Ts[(c0 + i * 4 + 1) * 72 + r] = f2bf(v.y);
        Ts[(c0 + i * 4 + 2) * 72 + r] = f2bf(v.z);
        Ts[(c0 + i * 4 + 3) * 72 + r] = f2bf(v.w);
    }
    __syncthreads();
#pragma unroll
    for (int i = 0; i < 2; i++) {
        int idx = i * 256 + tid;
        int row = idx >> 3, ko = (idx & 7) * 8;
        *(uint4*)(out + (size_t)(n0 + row) * DD + k0 + ko) =
            *(const uint4*)(Ts + row * 72 + ko);
    }
}

// ---------------------------------------------------------------------------
// K1b: adaln. grid (64 col-chunks of 32, 4 branches), block 256.
// ---------------------------------------------------------------------------
__global__ __launch_bounds__(256) void adaln_kernel(
    const float* __restrict__ emb,
    const float* __restrict__ adaln_w, const float* __restrict__ adaln_b,
    const float* __restrict__ xf_w, const float* __restrict__ xf_b,
    float* __restrict__ scaleB, float* __restrict__ shiftB)
{
    __shared__ __align__(16) float seT[EE][4];
    __shared__ float buf[128 * 33];
    int tid = threadIdx.x;
    int chunk = blockIdx.x, j = blockIdx.y;
#pragma unroll
    for (int b = 0; b < 4; b++) {
        float4 e4 = ((const float4*)(emb + (size_t)b * EE))[tid];
        seT[tid * 4 + 0][b] = e4.x / (1.f + __expf(-e4.x));
        seT[tid * 4 + 1][b] = e4.y / (1.f + __expf(-e4.y));
        seT[tid * 4 + 2][b] = e4.z / (1.f + __expf(-e4.z));
        seT[tid * 4 + 3][b] = e4.w / (1.f + __expf(-e4.w));
    }
    __syncthreads();
    const float* W    = (j < 3) ? (adaln_w + (size_t)j * EE * 2 * DD) : xf_w;
    const float* bias = (j < 3) ? (adaln_b + (size_t)j * 2 * DD) : xf_b;
    int eg = tid >> 3, cg = tid & 7;
    int c0 = chunk * 32 + cg * 4;
    const float* Wp = W + (size_t)(eg * 32) * (2 * DD) + c0;
    float4 a0 = {0,0,0,0}, a1 = {0,0,0,0}, a2 = {0,0,0,0}, a3 = {0,0,0,0};
#pragma unroll 8
    for (int e = 0; e < 32; e++) {
        float4 w = *(const float4*)(Wp + (size_t)e * (2 * DD));
        float4 s = *(const float4*)&seT[eg * 32 + e][0];
        a0.x += s.x * w.x; a0.y += s.x * w.y; a0.z += s.x * w.z; a0.w += s.x * w.w;
        a1.x += s.y * w.x; a1.y += s.y * w.y; a1.z += s.y * w.z; a1.w += s.y * w.w;
        a2.x += s.z * w.x; a2.y += s.z * w.y; a2.z += s.z * w.z; a2.w += s.z * w.w;
        a3.x += s.w * w.x; a3.y += s.w * w.y; a3.z += s.w * w.z; a3.w += s.w * w.w;
    }
    float accs[4][4] = {{a0.x,a0.y,a0.z,a0.w},{a1.x,a1.y,a1.z,a1.w},
                        {a2.x,a2.y,a2.z,a2.w},{a3.x,a3.y,a3.z,a3.w}};
#pragma unroll
    for (int b = 0; b < 4; b++)
#pragma unroll
        for (int i = 0; i < 4; i++)
            buf[(b * 32 + cg * 4 + i) * 33 + eg] = accs[b][i];
    __syncthreads();
    if (tid < 128) {
        int b = tid >> 5, cl = tid & 31;
        float s = 0.f;
#pragma unroll 8
        for (int e = 0; e < 32; e++) s += buf[(b * 32 + cl) * 33 + e];
        int c = chunk * 32 + cl;
        float v = s + bias[c];
        if (c < DD) scaleB[(size_t)(j * 4 + b) * DD + c] = v;
        else        shiftB[(size_t)(j * 4 + b) * DD + (c - DD)] = v;
    }
}

// ---------------------------------------------------------------------------
// K2: LayerNorm + modulate, cast bf16
// ---------------------------------------------------------------------------
__global__ __launch_bounds__(256) void ln_mod_kernel(
    const float* __restrict__ x1, const float* __restrict__ x2,
    const float* __restrict__ x3, const float* __restrict__ xf,
    const float* __restrict__ scaleB, const float* __restrict__ shiftB,
    unsigned short* __restrict__ hq, unsigned short* __restrict__ hx)
{
    __shared__ float rs[4], rq[4];
    int row = blockIdx.x, tid = threadIdx.x;
    const float* src; unsigned short* dst; int sb;
    if (row < 6144) {
        int b = row / 1536, t3 = row % 1536;
        int br = t3 >> 9, t = t3 & 511;
        const float* xs = (br == 0) ? x1 : ((br == 1) ? x2 : x3);
        src = xs + ((size_t)b * TSEQ + t) * DD;
        dst = hq + (size_t)row * DD;
        sb = br * 4 + b;
    } else {
        int idx = row - 6144;
        src = xf + (size_t)idx * DD;
        dst = hx + (size_t)idx * DD;
        sb = 12 + (idx >> 9);
    }
    float4 x = ((const float4*)src)[tid];
    float s = x.x + x.y + x.z + x.w;
    float q = x.x * x.x + x.y * x.y + x.z * x.z + x.w * x.w;
    for (int o = 1; o < 64; o <<= 1) { s += __shfl_xor(s, o, 64); q += __shfl_xor(q, o, 64); }
    int lane = tid & 63, wid = tid >> 6;
    if (lane == 0) { rs[wid] = s; rq[wid] = q; }
    __syncthreads();
    float S = rs[0] + rs[1] + rs[2] + rs[3];
    float Q = rq[0] + rq[1] + rq[2] + rq[3];
    float mu = S * (1.f / DD);
    float var = Q * (1.f / DD) - mu * mu;
    float rstd = rsqrtf(var + 1e-6f);
    float4 sc = ((const float4*)(scaleB + (size_t)sb * DD))[tid];
    float4 sh = ((const float4*)(shiftB + (size_t)sb * DD))[tid];
    ushort4 o;
    o.x = f2bf((x.x - mu) * rstd * (1.f + sc.x) + sh.x);
    o.y = f2bf((x.y - mu) * rstd * (1.f + sc.y) + sh.y);
    o.z = f2bf((x.z - mu) * rstd * (1.f + sc.z) + sh.z);
    o.w = f2bf((x.w - mu) * rstd * (1.f + sc.w) + sh.w);
    ((ushort4*)dst)[tid] = o;
}

// ---------------------------------------------------------------------------
// GEMM core: 128x128 tile, BK=64, global_load_lds staging, 4 waves 2x2 of 64x64.
// LDS layout [row][(chunk^(row&7))*8]: row stride 128B, XOR swizzle puts the
// 8 fragment chunks of a 16-lane group on all 32 banks (2 lanes/chunk = free).
// 32 MFMA per barrier pair (2x the BK=32 version) to amortize the vmcnt drain.
// ---------------------------------------------------------------------------
__device__ __forceinline__ void gemm_core(
    const unsigned short* __restrict__ A, const unsigned short* __restrict__ W,
    int m0, int n0, unsigned short* As, unsigned short* Bs,
    int tid, f32x4 acc[4][4])
{
    int lane = tid & 63, wid = tid >> 6;
    int fm = lane & 15, quad = lane >> 4;
    int wm = wid >> 1, wn = wid & 1;
    // staging: 256 threads = 32 rows x 8 chunks, 4 row-rounds per matrix
    int sr = tid >> 3;                    // row 0..31
    int sc = tid & 7;                     // LDS chunk position 0..7
    int gko = ((sc ^ (sr & 7)) * 8);      // global k-chunk that lands at pos sc
    const unsigned short* Ap = A + (size_t)(m0 + sr) * DD + gko;
    const unsigned short* Wp = W + (size_t)(n0 + sr) * DD + gko;
    unsigned short* la = As + tid * 8;    // = sr*64 + sc*8 (lane-contiguous)
    unsigned short* lb = Bs + tid * 8;
    int f7 = fm & 7;
    for (int k0 = 0; k0 < DD; k0 += 64) {
#pragma unroll
        for (int i = 0; i < 4; i++) {
            GLD16(Ap + (size_t)(32 * i) * DD + k0, la + i * 2048);
            GLD16(Wp + (size_t)(32 * i) * DD + k0, lb + i * 2048);
        }
        __syncthreads();
#pragma unroll
        for (int kh = 0; kh < 2; kh++) {
            int sq = ((quad + 4 * kh) ^ f7) * 8;
            bf16x8 af[4], bf[4];
#pragma unroll
            for (int mt = 0; mt < 4; mt++)
                af[mt] = *(const bf16x8*)(As + (wm * 64 + mt * 16 + fm) * 64 + sq);
#pragma unroll
            for (int nt = 0; nt < 4; nt++)
                bf[nt] = *(const bf16x8*)(Bs + (wn * 64 + nt * 16 + fm) * 64 + sq);
#pragma unroll
            for (int mt = 0; mt < 4; mt++)
#pragma unroll
                for (int nt = 0; nt < 4; nt++)
                    acc[mt][nt] = __builtin_amdgcn_mfma_f32_16x16x32_bf16(af[mt], bf[nt], acc[mt][nt], 0, 0, 0);
        }
        __syncthreads();
    }
}

// ---------------------------------------------------------------------------
// K3: fused Q/K/V projection -> MFMA-fragment-packed outputs.
// flat grid 640: m-tile = id % 80 (XCD-affine), n-tile = id / 80.
// ---------------------------------------------------------------------------
__global__ __launch_bounds__(256) void qkv_gemm(
    const unsigned short* __restrict__ hq, const unsigned short* __restrict__ hx,
    const unsigned short* __restrict__ qwt, const unsigned short* __restrict__ kwt,
    const unsigned short* __restrict__ vwt,
    const float* __restrict__ q_b, const float* __restrict__ k_b,
    const float* __restrict__ v_b,
    unsigned short* __restrict__ Qpk, unsigned short* __restrict__ Kpk,
    unsigned short* __restrict__ Vpk)
{
    __shared__ __align__(16) unsigned short As[128 * 64];
    __shared__ __align__(16) unsigned short Bs[128 * 64];
    int id = blockIdx.x;
    int ty = id % 80, n0 = (id / 80) * 128;
    const unsigned short *A, *W; const float* bias; int mode, m0;
    if (ty < 48) {
        m0 = ty * 128;
        int br = (m0 % 1536) >> 9;
        A = hq; W = qwt + (size_t)br * DD * DD; bias = q_b + (size_t)br * DD; mode = 0;
    } else if (ty < 64) {
        m0 = (ty - 48) * 128; A = hx; W = kwt; bias = k_b; mode = 1;
    } else {
        m0 = (ty - 64) * 128; A = hx; W = vwt; bias = v_b; mode = 2;
    }
    int tid = threadIdx.x, lane = tid & 63, wid = tid >> 6;
    int fm = lane & 15, quad = lane >> 4;
    int wm = wid >> 1, wn = wid & 1;
    f32x4 z = {0.f, 0.f, 0.f, 0.f};
    f32x4 acc[4][4];
#pragma unroll
    for (int mt = 0; mt < 4; mt++)
#pragma unroll
        for (int nt = 0; nt < 4; nt++) acc[mt][nt] = z;
    gemm_core(A, W, m0, n0, As, Bs, tid, acc);
#pragma unroll
    for (int mt = 0; mt < 4; mt++) {
#pragma unroll
        for (int nt = 0; nt < 4; nt++) {
            int c = n0 + wn * 64 + nt * 16 + fm;
            float bv = bias[c];
            int r0 = m0 + wm * 64 + mt * 16 + quad * 4;
            int h = c >> 6;
            if (mode == 0) {
                int b = r0 / 1536, t3 = r0 % 1536;
                int kk = (c >> 5) & 1, o = c & 31;
                size_t base = ((((size_t)(b * HH + h) * 2 + kk) * 1536) + t3) * 32 + o;
#pragma unroll
                for (int reg = 0; reg < 4; reg++)
                    Qpk[base + (size_t)reg * 32] = f2bf((acc[mt][nt][reg] + bv) * 0.125f);
            } else if (mode == 1) {
                int b = r0 >> 9, n = r0 & 511;
                int kk = (c >> 5) & 1, o = c & 31;
                size_t base = ((((size_t)(b * HH + h) * 2 + kk) * 512) + n) * 32 + o;
#pragma unroll
                for (int reg = 0; reg < 4; reg++)
                    Kpk[base + (size_t)reg * 32] = f2bf(acc[mt][nt][reg] + bv);
            } else {
                int b = r0 >> 9, n = r0 & 511;
                int hd = c & 63, cv = n >> 5, ko = n & 31;
                ushort4 st;
                st.x = f2bf(acc[mt][nt][0] + bv);
                st.y = f2bf(acc[mt][nt][1] + bv);
                st.z = f2bf(acc[mt][nt][2] + bv);
                st.w = f2bf(acc[mt][nt][3] + bv);
                *(ushort4*)(Vpk + ((((size_t)(b * HH + h) * 16 + cv) * 64) + hd) * 32 + ko) = st;
            }
        }
    }
}

// ---------------------------------------------------------------------------
// K5: out projection, fp32 out remapped branch-major. flat grid 384:
// m = id % 48 (XCD-affine), n = id / 48.
// ---------------------------------------------------------------------------
__global__ __launch_bounds__(256) void out_gemm(
    const unsigned short* __restrict__ Ain, const unsigned short* __restrict__ owt,
    const float* __restrict__ out_b, float* __restrict__ outp)
{
    __shared__ __align__(16) unsigned short As[128 * 64];
    __shared__ __align__(16) unsigned short Bs[128 * 64];
    int id = blockIdx.x;
    int m0 = (id % 48) * 128, n0 = (id / 48) * 128;
    int br = (m0 % 1536) >> 9;
    const unsigned short* W = owt + (size_t)br * DD * DD;
    const float* bias = out_b + (size_t)br * DD;
    int tid = threadIdx.x, lane = tid & 63, wid = tid >> 6;
    int fm = lane & 15, quad = lane >> 4;
    int wm = wid >> 1, wn = wid & 1;
    f32x4 z = {0.f, 0.f, 0.f, 0.f};
    f32x4 acc[4][4];
#pragma unroll
    for (int mt = 0; mt < 4; mt++)
#pragma unroll
        for (int nt = 0; nt < 4; nt++) acc[mt][nt] = z;
    gemm_core(Ain, W, m0, n0, As, Bs, tid, acc);
#pragma unroll
    for (int mt = 0; mt < 4; mt++) {
#pragma unroll
        for (int nt = 0; nt < 4; nt++) {
            int c = n0 + wn * 64 + nt * 16 + fm;
            float bv = bias[c];
            int r0 = m0 + wm * 64 + mt * 16 + quad * 4;
            int b = r0 / 1536, t3 = r0 % 1536, t = t3 & 511;
#pragma unroll
            for (int reg = 0; reg < 4; reg++)
                outp[(size_t)br * (BB * TSEQ * DD) + (size_t)b * (TSEQ * DD)
                     + (size_t)(t + reg) * DD + c] = acc[mt][nt][reg] + bv;
        }
    }
}

// ---------------------------------------------------------------------------
// K4: attention, 32 queries/block, packed-layout coalesced loads. grid (48, 64)
// ---------------------------------------------------------------------------
__global__ __launch_bounds__(256) void attn_kernel(
    const unsigned short* __restrict__ Qpk,
    const unsigned short* __restrict__ Kpk,
    const unsigned short* __restrict__ Vpk,
    const unsigned char* __restrict__ mask,
    unsigned short* __restrict__ attn)
{
    __shared__ __align__(16) unsigned short P[32 * 520];
    __shared__ float redsum[128];
    int bh = blockIdx.y, b = bh >> 4, h = bh & 15;
    int m0 = blockIdx.x * 32;
    int tid = threadIdx.x, lane = tid & 63, w = tid >> 6;
    int fm = lane & 15, quad = lane >> 4;

    const unsigned char* mp = mask + (size_t)b * NSEQ + w * 128;
    unsigned long long mw0 = __ballot(mp[lane] != 0);
    unsigned long long mw1 = __ballot(mp[64 + lane] != 0);

    // phase 1: S^T = K (Q/8)^T, mask as C-init, fully-coalesced fragment loads
    f32x4 acc[8][2];
#pragma unroll
    for (int mt = 0; mt < 8; mt++) {
        unsigned long long word = (mt >= 4) ? mw1 : mw0;
        int kb = (mt * 16 + quad * 4) & 63;
        f32x4 ini;
#pragma unroll
        for (int reg = 0; reg < 4; reg++)
            ini[reg] = ((word >> (kb + reg)) & 1ull) ? -1e30f : 0.f;
        acc[mt][0] = ini; acc[mt][1] = ini;
    }
    const unsigned short* Kbase = Kpk + (size_t)bh * 2 * 512 * 32 + quad * 8;
    const unsigned short* Qbase = Qpk + (size_t)bh * 2 * 1536 * 32 + quad * 8;
#pragma unroll
    for (int kk = 0; kk < 2; kk++) {
        bf16x8 bq0 = *(const bf16x8*)(Qbase + (size_t)(kk * 1536 + m0 + fm) * 32);
        bf16x8 bq1 = *(const bf16x8*)(Qbase + (size_t)(kk * 1536 + m0 + 16 + fm) * 32);
#pragma unroll
        for (int mt = 0; mt < 8; mt++) {
            bf16x8 ak = *(const bf16x8*)(Kbase + (size_t)(kk * 512 + w * 128 + mt * 16 + fm) * 32);
            acc[mt][0] = __builtin_amdgcn_mfma_f32_16x16x32_bf16(ak, bq0, acc[mt][0], 0, 0, 0);
            acc[mt][1] = __builtin_amdgcn_mfma_f32_16x16x32_bf16(ak, bq1, acc[mt][1], 0, 0, 0);
        }
    }

    // phase 2: e = exp(s), pack bf16 to LDS, column sums
    float s0 = 0.f, s1 = 0.f;
#pragma unroll
    for (int mt = 0; mt < 8; mt++) {
        float e00 = __expf(acc[mt][0][0]);
        float e01 = __expf(acc[mt][0][1]);
        float e02 = __expf(acc[mt][0][2]);
        float e03 = __expf(acc[mt][0][3]);
        float e10 = __expf(acc[mt][1][0]);
        float e11 = __expf(acc[mt][1][1]);
        float e12 = __expf(acc[mt][1][2]);
        float e13 = __expf(acc[mt][1][3]);
        s0 += (e00 + e01) + (e02 + e03);
        s1 += (e10 + e11) + (e12 + e13);
        uint2 p0, p1;
        p0.x = pkbf(e00, e01); p0.y = pkbf(e02, e03);
        p1.x = pkbf(e10, e11); p1.y = pkbf(e12, e13);
        int kb = w * 128 + mt * 16 + quad * 4;
        *(uint2*)(P + (size_t)fm * 520 + kb) = p0;
        *(uint2*)(P + (size_t)(16 + fm) * 520 + kb) = p1;
    }
    s0 += __shfl_xor(s0, 16, 64); s0 += __shfl_xor(s0, 32, 64);
    s1 += __shfl_xor(s1, 16, 64); s1 += __shfl_xor(s1, 32, 64);
    if (quad == 0) { redsum[w * 32 + fm] = s0; redsum[w * 32 + 16 + fm] = s1; }
    __syncthreads();

    // phase 3: O^T = V^T P (coalesced V fragments)
    float inv0 = 1.f / (redsum[fm] + redsum[32 + fm] + redsum[64 + fm] + redsum[96 + fm]);
    float inv1 = 1.f / (redsum[16 + fm] + redsum[48 + fm] + redsum[80 + fm] + redsum[112 + fm]);
    f32x4 z = {0.f, 0.f, 0.f, 0.f};
    f32x4 o0 = z, o1 = z;
    const unsigned short* Vbase = Vpk + (size_t)bh * 16 * 64 * 32 + (size_t)(w * 16 + fm) * 32 + quad * 8;
    const unsigned short* Pp0 = P + (size_t)fm * 520 + quad * 8;
    const unsigned short* Pp1 = P + (size_t)(16 + fm) * 520 + quad * 8;
#pragma unroll
    for (int kk = 0; kk < 16; kk++) {
        bf16x8 av = *(const bf16x8*)(Vbase + (size_t)kk * 64 * 32);
        bf16x8 p0 = *(const bf16x8*)(Pp0 + kk * 32);
        bf16x8 p1 = *(const bf16x8*)(Pp1 + kk * 32);
        o0 = __builtin_amdgcn_mfma_f32_16x16x32_bf16(av, p0, o0, 0, 0, 0);
        o1 = __builtin_amdgcn_mfma_f32_16x16x32_bf16(av, p1, o1, 0, 0, 0);
    }
    ushort4 r0, r1;
    r0.x = f2bf(o0[0] * inv0); r0.y = f2bf(o0[1] * inv0);
    r0.z = f2bf(o0[2] * inv0); r0.w = f2bf(o0[3] * inv0);
    r1.x = f2bf(o1[0] * inv1); r1.y = f2bf(o1[1] * inv1);
    r1.z = f2bf(o1[2] * inv1); r1.w = f2bf(o1[3] * inv1);
    *(ushort4*)(attn + ((size_t)(b * 1536 + m0 + fm)) * DD + h * HD + w * 16 + quad * 4) = r0;
    *(ushort4*)(attn + ((size_t)(b * 1536 + m0 + 16 + fm)) * DD + h * HD + w * 16 + quad * 4) = r1;
}

// ---------------------------------------------------------------------------
extern "C" void kernel_launch(void* const* d_in, const int* in_sizes, int n_in,
                              void* d_out, int out_size, void* d_ws, size_t ws_size,
                              hipStream_t stream)
{
    const float* x1   = (const float*)d_in[0];
    const float* x2   = (const float*)d_in[1];
    const float* x3   = (const float*)d_in[2];
    const float* xf   = (const float*)d_in[3];
    const float* emb  = (const float*)d_in[4];
    const unsigned char* mask = (const unsigned char*)d_in[5];
    const float* adaln_w = (const float*)d_in[6];
    const float* adaln_b = (const float*)d_in[7];
    const float* xf_w = (const float*)d_in[8];
    const float* xf_b = (const float*)d_in[9];
    const float* q_w  = (const float*)d_in[10];
    const float* q_b  = (const float*)d_in[11];
    const float* k_w  = (const float*)d_in[12];
    const float* k_b  = (const float*)d_in[13];
    const float* v_w  = (const float*)d_in[14];
    const float* v_b  = (const float*)d_in[15];
    const float* out_w = (const float*)d_in[16];
    const float* out_b = (const float*)d_in[17];

    char* ws = (char*)d_ws;
    float* scaleB        = (float*)(ws + 0);
    float* shiftB        = (float*)(ws + 65536);
    unsigned short* hq   = (unsigned short*)(ws + 131072);     // 12.58 MB (reused for attn out)
    unsigned short* hx   = (unsigned short*)(ws + 12713984);   // 4.19 MB
    unsigned short* Qpk  = (unsigned short*)(ws + 16908288);   // 12.58 MB
    unsigned short* Kpk  = (unsigned short*)(ws + 29491200);   // 4.19 MB
    unsigned short* Vpk  = (unsigned short*)(ws + 33685504);   // 4.19 MB
    unsigned short* qwt  = (unsigned short*)(ws + 37879808);   // 6.29 MB
    unsigned short* kwt  = (unsigned short*)(ws + 44171264);   // 2.10 MB
    unsigned short* vwt  = (unsigned short*)(ws + 46268416);   // 2.10 MB
    unsigned short* owt  = (unsigned short*)(ws + 48365568);   // 6.29 MB (end ~54.7 MB)

    tw_all_kernel<<<dim3(16, 16, 8), 256, 0, stream>>>(q_w, k_w, v_w, out_w,
                                                       qwt, kwt, vwt, owt);
    adaln_kernel<<<dim3(64, 4), 256, 0, stream>>>(emb, adaln_w, adaln_b, xf_w, xf_b,
                                                  scaleB, shiftB);
    ln_mod_kernel<<<8192, 256, 0, stream>>>(x1, x2, x3, xf, scaleB, shiftB, hq, hx);
    qkv_gemm<<<640, 256, 0, stream>>>(hq, hx, qwt, kwt, vwt, q_b, k_b, v_b,
                                      Qpk, Kpk, Vpk);
    attn_kernel<<<dim3(48, 64), 256, 0, stream>>>(Qpk, Kpk, Vpk, mask, hq);
    out_gemm<<<384, 256, 0, stream>>>(hq, owt, out_b, (float*)d_out);
}

// Round 8
// 263.384 us; speedup vs baseline: 1.1971x; 1.0392x over previous
//
#include <hip/hip_runtime.h>
#include <hip/hip_bf16.h>
#include <stdint.h>

#define BB 4
#define TSEQ 512
#define NSEQ 512
#define DD 1024
#define EE 1024
#define HH 16
#define HD 64

typedef __attribute__((ext_vector_type(8))) short bf16x8;
typedef __attribute__((ext_vector_type(4))) float f32x4;

__device__ __forceinline__ unsigned short f2bf(float f) {
    union { float f; uint32_t u; } v; v.f = f;
    uint32_t u = v.u;
    uint32_t r = (u + 0x7fffu + ((u >> 16) & 1u)) >> 16;
    return (unsigned short)r;
}

__device__ __forceinline__ uint32_t pkbf(float a, float b) {
    __hip_bfloat162 t = __float22bfloat162_rn(float2{a, b});
    return *(uint32_t*)&t;
}

#define GLD16(gp, lp)                                                          \
    __builtin_amdgcn_global_load_lds(                                          \
        (const __attribute__((address_space(1))) unsigned int*)(gp),           \
        (__attribute__((address_space(3))) unsigned int*)(lp), 16, 0, 0)

// ---------------------------------------------------------------------------
// K1a: fused weight transpose+cvt for all 4 weight tensors
// ---------------------------------------------------------------------------
__global__ __launch_bounds__(256) void tw_all_kernel(
    const float* __restrict__ q_w, const float* __restrict__ k_w,
    const float* __restrict__ v_w, const float* __restrict__ out_w,
    unsigned short* __restrict__ qwt, unsigned short* __restrict__ kwt,
    unsigned short* __restrict__ vwt, unsigned short* __restrict__ owt)
{
    __shared__ __align__(16) unsigned short Ts[64 * 72];
    int k0 = blockIdx.x * 64, n0 = blockIdx.y * 64;
    int z = blockIdx.z;
    const float* in; unsigned short* out;
    if (z < 3)       { in = q_w + (size_t)z * DD * DD;         out = qwt + (size_t)z * DD * DD; }
    else if (z == 3) { in = k_w;                               out = kwt; }
    else if (z == 4) { in = v_w;                               out = vwt; }
    else             { in = out_w + (size_t)(z - 5) * DD * DD; out = owt + (size_t)(z - 5) * DD * DD; }
    int tid = threadIdx.x;
    int r = tid >> 2, c0 = (tid & 3) * 16;
#pragma unroll
    for (int i = 0; i < 4; i++) {
        float4 v = *(const float4*)(in + (size_t)(k0 + r) * DD + n0 + c0 + i * 4);
        Ts[(c0 + i * 4 + 0) * 72 + r] = f2bf(v.x);
        Ts[(c0 + i * 4 + 1) * 72 + r] = f2bf(v.y);
        Ts[(c0 + i * 4 + 2) * 72 + r] = f2bf(v.z);
        Ts[(c0 + i * 4 + 3) * 72 + r] = f2bf(v.w);
    }
    __syncthreads();
#pragma unroll
    for (int i = 0; i < 2; i++) {
        int idx = i * 256 + tid;
        int row = idx >> 3, ko = (idx & 7) * 8;
        *(uint4*)(out + (size_t)(n0 + row) * DD + k0 + ko) =
            *(const uint4*)(Ts + row * 72 + ko);
    }
}

// ---------------------------------------------------------------------------
// K1b: adaln. grid (64 col-chunks of 32, 4 branches), block 256.
// ---------------------------------------------------------------------------
__global__ __launch_bounds__(256) void adaln_kernel(
    const float* __restrict__ emb,
    const float* __restrict__ adaln_w, const float* __restrict__ adaln_b,
    const float* __restrict__ xf_w, const float* __restrict__ xf_b,
    float* __restrict__ scaleB, float* __restrict__ shiftB)
{
    __shared__ __align__(16) float seT[EE][4];
    __shared__ float buf[128 * 33];
    int tid = threadIdx.x;
    int chunk = blockIdx.x, j = blockIdx.y;
#pragma unroll
    for (int b = 0; b < 4; b++) {
        float4 e4 = ((const float4*)(emb + (size_t)b * EE))[tid];
        seT[tid * 4 + 0][b] = e4.x / (1.f + __expf(-e4.x));
        seT[tid * 4 + 1][b] = e4.y / (1.f + __expf(-e4.y));
        seT[tid * 4 + 2][b] = e4.z / (1.f + __expf(-e4.z));
        seT[tid * 4 + 3][b] = e4.w / (1.f + __expf(-e4.w));
    }
    __syncthreads();
    const float* W    = (j < 3) ? (adaln_w + (size_t)j * EE * 2 * DD) : xf_w;
    const float* bias = (j < 3) ? (adaln_b + (size_t)j * 2 * DD) : xf_b;
    int eg = tid >> 3, cg = tid & 7;
    int c0 = chunk * 32 + cg * 4;
    const float* Wp = W + (size_t)(eg * 32) * (2 * DD) + c0;
    float4 a0 = {0,0,0,0}, a1 = {0,0,0,0}, a2 = {0,0,0,0}, a3 = {0,0,0,0};
#pragma unroll 8
    for (int e = 0; e < 32; e++) {
        float4 w = *(const float4*)(Wp + (size_t)e * (2 * DD));
        float4 s = *(const float4*)&seT[eg * 32 + e][0];
        a0.x += s.x * w.x; a0.y += s.x * w.y; a0.z += s.x * w.z; a0.w += s.x * w.w;
        a1.x += s.y * w.x; a1.y += s.y * w.y; a1.z += s.y * w.z; a1.w += s.y * w.w;
        a2.x += s.z * w.x; a2.y += s.z * w.y; a2.z += s.z * w.z; a2.w += s.z * w.w;
        a3.x += s.w * w.x; a3.y += s.w * w.y; a3.z += s.w * w.z; a3.w += s.w * w.w;
    }
    float accs[4][4] = {{a0.x,a0.y,a0.z,a0.w},{a1.x,a1.y,a1.z,a1.w},
                        {a2.x,a2.y,a2.z,a2.w},{a3.x,a3.y,a3.z,a3.w}};
#pragma unroll
    for (int b = 0; b < 4; b++)
#pragma unroll
        for (int i = 0; i < 4; i++)
            buf[(b * 32 + cg * 4 + i) * 33 + eg] = accs[b][i];
    __syncthreads();
    if (tid < 128) {
        int b = tid >> 5, cl = tid & 31;
        float s = 0.f;
#pragma unroll 8
        for (int e = 0; e < 32; e++) s += buf[(b * 32 + cl) * 33 + e];
        int c = chunk * 32 + cl;
        float v = s + bias[c];
        if (c < DD) scaleB[(size_t)(j * 4 + b) * DD + c] = v;
        else        shiftB[(size_t)(j * 4 + b) * DD + (c - DD)] = v;
    }
}

// ---------------------------------------------------------------------------
// K2: LayerNorm + modulate, cast bf16
// ---------------------------------------------------------------------------
__global__ __launch_bounds__(256) void ln_mod_kernel(
    const float* __restrict__ x1, const float* __restrict__ x2,
    const float* __restrict__ x3, const float* __restrict__ xf,
    const float* __restrict__ scaleB, const float* __restrict__ shiftB,
    unsigned short* __restrict__ hq, unsigned short* __restrict__ hx)
{
    __shared__ float rs[4], rq[4];
    int row = blockIdx.x, tid = threadIdx.x;
    const float* src; unsigned short* dst; int sb;
    if (row < 6144) {
        int b = row / 1536, t3 = row % 1536;
        int br = t3 >> 9, t = t3 & 511;
        const float* xs = (br == 0) ? x1 : ((br == 1) ? x2 : x3);
        src = xs + ((size_t)b * TSEQ + t) * DD;
        dst = hq + (size_t)row * DD;
        sb = br * 4 + b;
    } else {
        int idx = row - 6144;
        src = xf + (size_t)idx * DD;
        dst = hx + (size_t)idx * DD;
        sb = 12 + (idx >> 9);
    }
    float4 x = ((const float4*)src)[tid];
    float s = x.x + x.y + x.z + x.w;
    float q = x.x * x.x + x.y * x.y + x.z * x.z + x.w * x.w;
    for (int o = 1; o < 64; o <<= 1) { s += __shfl_xor(s, o, 64); q += __shfl_xor(q, o, 64); }
    int lane = tid & 63, wid = tid >> 6;
    if (lane == 0) { rs[wid] = s; rq[wid] = q; }
    __syncthreads();
    float S = rs[0] + rs[1] + rs[2] + rs[3];
    float Q = rq[0] + rq[1] + rq[2] + rq[3];
    float mu = S * (1.f / DD);
    float var = Q * (1.f / DD) - mu * mu;
    float rstd = rsqrtf(var + 1e-6f);
    float4 sc = ((const float4*)(scaleB + (size_t)sb * DD))[tid];
    float4 sh = ((const float4*)(shiftB + (size_t)sb * DD))[tid];
    ushort4 o;
    o.x = f2bf((x.x - mu) * rstd * (1.f + sc.x) + sh.x);
    o.y = f2bf((x.y - mu) * rstd * (1.f + sc.y) + sh.y);
    o.z = f2bf((x.z - mu) * rstd * (1.f + sc.z) + sh.z);
    o.w = f2bf((x.w - mu) * rstd * (1.f + sc.w) + sh.w);
    ((ushort4*)dst)[tid] = o;
}

// ---------------------------------------------------------------------------
// GEMM core: 128x64 tile, BK=64, conflict-free XOR swizzle, 4 waves 2x2.
// Smaller tile -> more blocks/CU (grid 1280/768 = 5/3 per CU, even) so
// inter-block wave overlap hides the vmcnt(0)+barrier drain (m114).
// ---------------------------------------------------------------------------
__device__ __forceinline__ void gemm_core64(
    const unsigned short* __restrict__ A, const unsigned short* __restrict__ W,
    int m0, int n0, unsigned short* As, unsigned short* Bs,
    int tid, f32x4 acc[4][2])
{
    int lane = tid & 63, wid = tid >> 6;
    int fm = lane & 15, quad = lane >> 4;
    int wm = wid >> 1, wn = wid & 1;
    int sr = tid >> 3;                    // row 0..31
    int sc = tid & 7;                     // LDS chunk position 0..7
    int gko = (sc ^ (sr & 7)) * 8;        // global k-chunk landing at pos sc
    const unsigned short* Ap = A + (size_t)(m0 + sr) * DD + gko;
    const unsigned short* Wp = W + (size_t)(n0 + sr) * DD + gko;
    unsigned short* la = As + tid * 8;    // = sr*64 + sc*8
    unsigned short* lb = Bs + tid * 8;
    int f7 = fm & 7;
    for (int k0 = 0; k0 < DD; k0 += 64) {
#pragma unroll
        for (int i = 0; i < 4; i++)
            GLD16(Ap + (size_t)(32 * i) * DD + k0, la + i * 2048);
#pragma unroll
        for (int i = 0; i < 2; i++)
            GLD16(Wp + (size_t)(32 * i) * DD + k0, lb + i * 2048);
        __syncthreads();
#pragma unroll
        for (int kh = 0; kh < 2; kh++) {
            int sq = ((quad + 4 * kh) ^ f7) * 8;
            bf16x8 af[4], bfr[2];
#pragma unroll
            for (int mt = 0; mt < 4; mt++)
                af[mt] = *(const bf16x8*)(As + (wm * 64 + mt * 16 + fm) * 64 + sq);
#pragma unroll
            for (int nt = 0; nt < 2; nt++)
                bfr[nt] = *(const bf16x8*)(Bs + (wn * 32 + nt * 16 + fm) * 64 + sq);
#pragma unroll
            for (int mt = 0; mt < 4; mt++)
#pragma unroll
                for (int nt = 0; nt < 2; nt++)
                    acc[mt][nt] = __builtin_amdgcn_mfma_f32_16x16x32_bf16(af[mt], bfr[nt], acc[mt][nt], 0, 0, 0);
        }
        __syncthreads();
    }
}

// ---------------------------------------------------------------------------
// K3: fused Q/K/V projection -> MFMA-fragment-packed outputs.
// flat grid 1280: m-tile = id % 80 (XCD-affine), n-tile(64) = id / 80.
// ---------------------------------------------------------------------------
__global__ __launch_bounds__(256) void qkv_gemm(
    const unsigned short* __restrict__ hq, const unsigned short* __restrict__ hx,
    const unsigned short* __restrict__ qwt, const unsigned short* __restrict__ kwt,
    const unsigned short* __restrict__ vwt,
    const float* __restrict__ q_b, const float* __restrict__ k_b,
    const float* __restrict__ v_b,
    unsigned short* __restrict__ Qpk, unsigned short* __restrict__ Kpk,
    unsigned short* __restrict__ Vpk)
{
    __shared__ __align__(16) unsigned short As[128 * 64];
    __shared__ __align__(16) unsigned short Bs[64 * 64];
    int id = blockIdx.x;
    int ty = id % 80, n0 = (id / 80) * 64;
    const unsigned short *A, *W; const float* bias; int mode, m0;
    if (ty < 48) {
        m0 = ty * 128;
        int br = (m0 % 1536) >> 9;
        A = hq; W = qwt + (size_t)br * DD * DD; bias = q_b + (size_t)br * DD; mode = 0;
    } else if (ty < 64) {
        m0 = (ty - 48) * 128; A = hx; W = kwt; bias = k_b; mode = 1;
    } else {
        m0 = (ty - 64) * 128; A = hx; W = vwt; bias = v_b; mode = 2;
    }
    int tid = threadIdx.x, lane = tid & 63, wid = tid >> 6;
    int fm = lane & 15, quad = lane >> 4;
    int wm = wid >> 1, wn = wid & 1;
    f32x4 z = {0.f, 0.f, 0.f, 0.f};
    f32x4 acc[4][2];
#pragma unroll
    for (int mt = 0; mt < 4; mt++)
#pragma unroll
        for (int nt = 0; nt < 2; nt++) acc[mt][nt] = z;
    gemm_core64(A, W, m0, n0, As, Bs, tid, acc);
#pragma unroll
    for (int mt = 0; mt < 4; mt++) {
#pragma unroll
        for (int nt = 0; nt < 2; nt++) {
            int c = n0 + wn * 32 + nt * 16 + fm;
            float bv = bias[c];
            int r0 = m0 + wm * 64 + mt * 16 + quad * 4;
            int h = c >> 6;
            if (mode == 0) {
                int b = r0 / 1536, t3 = r0 % 1536;
                int kk = (c >> 5) & 1, o = c & 31;
                size_t base = ((((size_t)(b * HH + h) * 2 + kk) * 1536) + t3) * 32 + o;
#pragma unroll
                for (int reg = 0; reg < 4; reg++)
                    Qpk[base + (size_t)reg * 32] = f2bf((acc[mt][nt][reg] + bv) * 0.125f);
            } else if (mode == 1) {
                int b = r0 >> 9, n = r0 & 511;
                int kk = (c >> 5) & 1, o = c & 31;
                size_t base = ((((size_t)(b * HH + h) * 2 + kk) * 512) + n) * 32 + o;
#pragma unroll
                for (int reg = 0; reg < 4; reg++)
                    Kpk[base + (size_t)reg * 32] = f2bf(acc[mt][nt][reg] + bv);
            } else {
                int b = r0 >> 9, n = r0 & 511;
                int hd = c & 63, cv = n >> 5, ko = n & 31;
                ushort4 st;
                st.x = f2bf(acc[mt][nt][0] + bv);
                st.y = f2bf(acc[mt][nt][1] + bv);
                st.z = f2bf(acc[mt][nt][2] + bv);
                st.w = f2bf(acc[mt][nt][3] + bv);
                *(ushort4*)(Vpk + ((((size_t)(b * HH + h) * 16 + cv) * 64) + hd) * 32 + ko) = st;
            }
        }
    }
}

// ---------------------------------------------------------------------------
// K5: out projection, fp32 out remapped branch-major. flat grid 768:
// m = id % 48 (XCD-affine), n-tile(64) = id / 48.
// ---------------------------------------------------------------------------
__global__ __launch_bounds__(256) void out_gemm(
    const unsigned short* __restrict__ Ain, const unsigned short* __restrict__ owt,
    const float* __restrict__ out_b, float* __restrict__ outp)
{
    __shared__ __align__(16) unsigned short As[128 * 64];
    __shared__ __align__(16) unsigned short Bs[64 * 64];
    int id = blockIdx.x;
    int m0 = (id % 48) * 128, n0 = (id / 48) * 64;
    int br = (m0 % 1536) >> 9;
    const unsigned short* W = owt + (size_t)br * DD * DD;
    const float* bias = out_b + (size_t)br * DD;
    int tid = threadIdx.x, lane = tid & 63, wid = tid >> 6;
    int fm = lane & 15, quad = lane >> 4;
    int wm = wid >> 1, wn = wid & 1;
    f32x4 z = {0.f, 0.f, 0.f, 0.f};
    f32x4 acc[4][2];
#pragma unroll
    for (int mt = 0; mt < 4; mt++)
#pragma unroll
        for (int nt = 0; nt < 2; nt++) acc[mt][nt] = z;
    gemm_core64(Ain, W, m0, n0, As, Bs, tid, acc);
#pragma unroll
    for (int mt = 0; mt < 4; mt++) {
#pragma unroll
        for (int nt = 0; nt < 2; nt++) {
            int c = n0 + wn * 32 + nt * 16 + fm;
            float bv = bias[c];
            int r0 = m0 + wm * 64 + mt * 16 + quad * 4;
            int b = r0 / 1536, t3 = r0 % 1536, t = t3 & 511;
#pragma unroll
            for (int reg = 0; reg < 4; reg++)
                outp[(size_t)br * (BB * TSEQ * DD) + (size_t)b * (TSEQ * DD)
                     + (size_t)(t + reg) * DD + c] = acc[mt][nt][reg] + bv;
        }
    }
}

// ---------------------------------------------------------------------------
// K4: attention, 32 queries/block, packed-layout coalesced loads. grid (48, 64)
// ---------------------------------------------------------------------------
__global__ __launch_bounds__(256) void attn_kernel(
    const unsigned short* __restrict__ Qpk,
    const unsigned short* __restrict__ Kpk,
    const unsigned short* __restrict__ Vpk,
    const unsigned char* __restrict__ mask,
    unsigned short* __restrict__ attn)
{
    __shared__ __align__(16) unsigned short P[32 * 520];
    __shared__ float redsum[128];
    int bh = blockIdx.y, b = bh >> 4, h = bh & 15;
    int m0 = blockIdx.x * 32;
    int tid = threadIdx.x, lane = tid & 63, w = tid >> 6;
    int fm = lane & 15, quad = lane >> 4;

    const unsigned char* mp = mask + (size_t)b * NSEQ + w * 128;
    unsigned long long mw0 = __ballot(mp[lane] != 0);
    unsigned long long mw1 = __ballot(mp[64 + lane] != 0);

    // phase 1: S^T = K (Q/8)^T, mask as C-init, fully-coalesced fragment loads
    f32x4 acc[8][2];
#pragma unroll
    for (int mt = 0; mt < 8; mt++) {
        unsigned long long word = (mt >= 4) ? mw1 : mw0;
        int kb = (mt * 16 + quad * 4) & 63;
        f32x4 ini;
#pragma unroll
        for (int reg = 0; reg < 4; reg++)
            ini[reg] = ((word >> (kb + reg)) & 1ull) ? -1e30f : 0.f;
        acc[mt][0] = ini; acc[mt][1] = ini;
    }
    const unsigned short* Kbase = Kpk + (size_t)bh * 2 * 512 * 32 + quad * 8;
    const unsigned short* Qbase = Qpk + (size_t)bh * 2 * 1536 * 32 + quad * 8;
#pragma unroll
    for (int kk = 0; kk < 2; kk++) {
        bf16x8 bq0 = *(const bf16x8*)(Qbase + (size_t)(kk * 1536 + m0 + fm) * 32);
        bf16x8 bq1 = *(const bf16x8*)(Qbase + (size_t)(kk * 1536 + m0 + 16 + fm) * 32);
#pragma unroll
        for (int mt = 0; mt < 8; mt++) {
            bf16x8 ak = *(const bf16x8*)(Kbase + (size_t)(kk * 512 + w * 128 + mt * 16 + fm) * 32);
            acc[mt][0] = __builtin_amdgcn_mfma_f32_16x16x32_bf16(ak, bq0, acc[mt][0], 0, 0, 0);
            acc[mt][1] = __builtin_amdgcn_mfma_f32_16x16x32_bf16(ak, bq1, acc[mt][1], 0, 0, 0);
        }
    }

    // phase 2: e = exp(s), pack bf16 to LDS, column sums
    float s0 = 0.f, s1 = 0.f;
#pragma unroll
    for (int mt = 0; mt < 8; mt++) {
        float e00 = __expf(acc[mt][0][0]);
        float e01 = __expf(acc[mt][0][1]);
        float e02 = __expf(acc[mt][0][2]);
        float e03 = __expf(acc[mt][0][3]);
        float e10 = __expf(acc[mt][1][0]);
        float e11 = __expf(acc[mt][1][1]);
        float e12 = __expf(acc[mt][1][2]);
        float e13 = __expf(acc[mt][1][3]);
        s0 += (e00 + e01) + (e02 + e03);
        s1 += (e10 + e11) + (e12 + e13);
        uint2 p0, p1;
        p0.x = pkbf(e00, e01); p0.y = pkbf(e02, e03);
        p1.x = pkbf(e10, e11); p1.y = pkbf(e12, e13);
        int kb = w * 128 + mt * 16 + quad * 4;
        *(uint2*)(P + (size_t)fm * 520 + kb) = p0;
        *(uint2*)(P + (size_t)(16 + fm) * 520 + kb) = p1;
    }
    s0 += __shfl_xor(s0, 16, 64); s0 += __shfl_xor(s0, 32, 64);
    s1 += __shfl_xor(s1, 16, 64); s1 += __shfl_xor(s1, 32, 64);
    if (quad == 0) { redsum[w * 32 + fm] = s0; redsum[w * 32 + 16 + fm] = s1; }
    __syncthreads();

    // phase 3: O^T = V^T P (coalesced V fragments)
    float inv0 = 1.f / (redsum[fm] + redsum[32 + fm] + redsum[64 + fm] + redsum[96 + fm]);
    float inv1 = 1.f / (redsum[16 + fm] + redsum[48 + fm] + redsum[80 + fm] + redsum[112 + fm]);
    f32x4 z = {0.f, 0.f, 0.f, 0.f};
    f32x4 o0 = z, o1 = z;
    const unsigned short* Vbase = Vpk + (size_t)bh * 16 * 64 * 32 + (size_t)(w * 16 + fm) * 32 + quad * 8;
    const unsigned short* Pp0 = P + (size_t)fm * 520 + quad * 8;
    const unsigned short* Pp1 = P + (size_t)(16 + fm) * 520 + quad * 8;
#pragma unroll
    for (int kk = 0; kk < 16; kk++) {
        bf16x8 av = *(const bf16x8*)(Vbase + (size_t)kk * 64 * 32);
        bf16x8 p0 = *(const bf16x8*)(Pp0 + kk * 32);
        bf16x8 p1 = *(const bf16x8*)(Pp1 + kk * 32);
        o0 = __builtin_amdgcn_mfma_f32_16x16x32_bf16(av, p0, o0, 0, 0, 0);
        o1 = __builtin_amdgcn_mfma_f32_16x16x32_bf16(av, p1, o1, 0, 0, 0);
    }
    ushort4 r0, r1;
    r0.x = f2bf(o0[0] * inv0); r0.y = f2bf(o0[1] * inv0);
    r0.z = f2bf(o0[2] * inv0); r0.w = f2bf(o0[3] * inv0);
    r1.x = f2bf(o1[0] * inv1); r1.y = f2bf(o1[1] * inv1);
    r1.z = f2bf(o1[2] * inv1); r1.w = f2bf(o1[3] * inv1);
    *(ushort4*)(attn + ((size_t)(b * 1536 + m0 + fm)) * DD + h * HD + w * 16 + quad * 4) = r0;
    *(ushort4*)(attn + ((size_t)(b * 1536 + m0 + 16 + fm)) * DD + h * HD + w * 16 + quad * 4) = r1;
}

// ---------------------------------------------------------------------------
extern "C" void kernel_launch(void* const* d_in, const int* in_sizes, int n_in,
                              void* d_out, int out_size, void* d_ws, size_t ws_size,
                              hipStream_t stream)
{
    const float* x1   = (const float*)d_in[0];
    const float* x2   = (const float*)d_in[1];
    const float* x3   = (const float*)d_in[2];
    const float* xf   = (const float*)d_in[3];
    const float* emb  = (const float*)d_in[4];
    const unsigned char* mask = (const unsigned char*)d_in[5];
    const float* adaln_w = (const float*)d_in[6];
    const float* adaln_b = (const float*)d_in[7];
    const float* xf_w = (const float*)d_in[8];
    const float* xf_b = (const float*)d_in[9];
    const float* q_w  = (const float*)d_in[10];
    const float* q_b  = (const float*)d_in[11];
    const float* k_w  = (const float*)d_in[12];
    const float* k_b  = (const float*)d_in[13];
    const float* v_w  = (const float*)d_in[14];
    const float* v_b  = (const float*)d_in[15];
    const float* out_w = (const float*)d_in[16];
    const float* out_b = (const float*)d_in[17];

    char* ws = (char*)d_ws;
    float* scaleB        = (float*)(ws + 0);
    float* shiftB        = (float*)(ws + 65536);
    unsigned short* hq   = (unsigned short*)(ws + 131072);     // 12.58 MB (reused for attn out)
    unsigned short* hx   = (unsigned short*)(ws + 12713984);   // 4.19 MB
    unsigned short* Qpk  = (unsigned short*)(ws + 16908288);   // 12.58 MB
    unsigned short* Kpk  = (unsigned short*)(ws + 29491200);   // 4.19 MB
    unsigned short* Vpk  = (unsigned short*)(ws + 33685504);   // 4.19 MB
    unsigned short* qwt  = (unsigned short*)(ws + 37879808);   // 6.29 MB
    unsigned short* kwt  = (unsigned short*)(ws + 44171264);   // 2.10 MB
    unsigned short* vwt  = (unsigned short*)(ws + 46268416);   // 2.10 MB
    unsigned short* owt  = (unsigned short*)(ws + 48365568);   // 6.29 MB (end ~54.7 MB)

    tw_all_kernel<<<dim3(16, 16, 8), 256, 0, stream>>>(q_w, k_w, v_w, out_w,
                                                       qwt, kwt, vwt, owt);
    adaln_kernel<<<dim3(64, 4), 256, 0, stream>>>(emb, adaln_w, adaln_b, xf_w, xf_b,
                                                  scaleB, shiftB);
    ln_mod_kernel<<<8192, 256, 0, stream>>>(x1, x2, x3, xf, scaleB, shiftB, hq, hx);
    qkv_gemm<<<1280, 256, 0, stream>>>(hq, hx, qwt, kwt, vwt, q_b, k_b, v_b,
                                       Qpk, Kpk, Vpk);
    attn_kernel<<<dim3(48, 64), 256, 0, stream>>>(Qpk, Kpk, Vpk, mask, hq);
    out_gemm<<<768, 256, 0, stream>>>(hq, owt, out_b, (float*)d_out);
}